// Round 3
// baseline (281.473 us; speedup 1.0000x reference)
//
#include <hip/hip_runtime.h>
#include <math.h>

#define N_NODES 50000
#define N_EDGES 800000
#define NFEAT 256
#define HID 64
#define NCLS 40
#define EPS_RES 0.3f
#define ROWSZ 68  // LDS row pitch for proj (64 + 4 pad)
#define SCAN_BLOCKS ((N_NODES + 255) / 256)  // 196
#define EB 32                 // edge chunks
#define CHUNK (N_EDGES / EB)  // 25000
#define NR 4                  // node ranges
#define RNG (N_NODES / NR)    // 12500 -> 50KB LDS histogram

typedef unsigned int uint;
typedef unsigned short ushort;

__device__ __forceinline__ float bflo(uint u) { return __uint_as_float(u << 16); }
__device__ __forceinline__ float bfhi(uint u) { return __uint_as_float(u & 0xFFFF0000u); }
__device__ __forceinline__ uint bf16rne(float f) {
    uint u = __float_as_uint(f);
    return (u + 0x7FFFu + ((u >> 16) & 1u)) >> 16;
}
__device__ __forceinline__ uint bf16rne2(float a, float b) {
    return bf16rne(a) | (bf16rne(b) << 16);
}

// tanh(x) = 1 - 2/(e^{2x}+1) via v_exp_f32 + v_rcp_f32 (~2 ulp; exact +-1 limits).
__device__ __forceinline__ float fast_tanh(float x) {
    float t = __builtin_amdgcn_exp2f(x * 2.885390081777927f);  // e^{2x}
    return 1.0f - 2.0f * __builtin_amdgcn_rcpf(t + 1.0f);
}

// ---------------- degree histograms via LDS binning: ZERO global atomics ----------------
__global__ __launch_bounds__(256) void hist_kernel(const int* __restrict__ row,
                                                   const int* __restrict__ col,
                                                   int* __restrict__ degM,
                                                   int* __restrict__ cntM,
                                                   int* __restrict__ rank_local) {
    __shared__ int hist[RNG];
    int t = threadIdx.x;
    int chunk = blockIdx.x;
    int lo = blockIdx.y * RNG;
    int side = blockIdx.z;
    for (int j = t; j < RNG; j += 256) hist[j] = 0;
    __syncthreads();
    const int* idx = side ? col : row;
    int e0 = chunk * CHUNK;
    if (side == 0) {
        for (int base = 0; base < CHUNK; base += 1024) {
            int vb[4];
#pragma unroll
            for (int j = 0; j < 4; j++) {
                int i = base + j * 256 + t;
                vb[j] = (i < CHUNK) ? idx[e0 + i] : -1;
            }
#pragma unroll
            for (int j = 0; j < 4; j++) {
                uint v = (uint)(vb[j] - lo);
                if (v < RNG) atomicAdd(&hist[v], 1);
            }
        }
    } else {
        for (int base = 0; base < CHUNK; base += 1024) {
            int vb[4], ib[4];
#pragma unroll
            for (int j = 0; j < 4; j++) {
                int i = base + j * 256 + t;
                ib[j] = i;
                vb[j] = (i < CHUNK) ? idx[e0 + i] : -1;
            }
#pragma unroll
            for (int j = 0; j < 4; j++) {
                uint v = (uint)(vb[j] - lo);
                if (v < RNG) rank_local[e0 + ib[j]] = atomicAdd(&hist[v], 1);
            }
        }
    }
    __syncthreads();
    int* M = side ? cntM : degM;
    for (int j = t; j < RNG; j += 256) M[chunk * N_NODES + lo + j] = hist[j];
}

// ---------------- scan1: chunk-reduce (nd/invcnt + in-place cntM bases) + block scan ----
__device__ __forceinline__ int block_excl_scan_256(int v, int t, int* wsum) {
    int lane = t & 63, w = t >> 6;
    int sv = v;
#pragma unroll
    for (int d = 1; d < 64; d <<= 1) {
        int o = __shfl_up(sv, d);
        if (lane >= d) sv += o;
    }
    if (lane == 63) wsum[w] = sv;
    __syncthreads();
    int add = 0;
    for (int i = 0; i < w; i++) add += wsum[i];
    return sv + add - v;
}

__global__ void scan1_kernel(const int* __restrict__ degM, int* __restrict__ cntM,
                             int* __restrict__ off, int* __restrict__ bsum,
                             float* __restrict__ nd, float* __restrict__ invcnt) {
    __shared__ int wsum[4];
    int t = threadIdx.x;
    int idx = blockIdx.x * 256 + t;
    int v = 0;
    if (idx < N_NODES) {
        int sD = 0;
#pragma unroll
        for (int c = 0; c < EB; c++) sD += degM[c * N_NODES + idx];
        int run = 0;
#pragma unroll
        for (int c = 0; c < EB; c++) {
            int cv = cntM[c * N_NODES + idx];
            cntM[c * N_NODES + idx] = run;  // exclusive base for this chunk within bucket
            run += cv;
        }
        v = run;
        if (sD < 1) sD = 1;
        nd[idx] = rsqrtf((float)sD);
        int cc = run; if (cc < 1) cc = 1;
        invcnt[idx] = 1.0f / (float)cc;
    }
    int excl = block_excl_scan_256(v, t, wsum);
    if (idx < N_NODES) off[idx] = excl;
    if (t == 255) bsum[blockIdx.x] = excl + v;
}

__global__ void scan2_kernel(int* __restrict__ bsum) {
    __shared__ int wsum[4];
    int t = threadIdx.x;
    int v = (t < SCAN_BLOCKS) ? bsum[t] : 0;
    int excl = block_excl_scan_256(v, t, wsum);
    if (t < SCAN_BLOCKS) bsum[t] = excl;
}

__global__ void scan3_kernel(int* __restrict__ off, const int* __restrict__ bsum) {
    int t = threadIdx.x;
    int idx = blockIdx.x * 256 + t;
    if (idx < N_NODES) off[idx] += bsum[blockIdx.x];
    if (idx == 0) off[N_NODES] = N_EDGES;
}

// ---------------- CSR scatter: atomic-free, one 8B store per edge (+dst record) ----------
__global__ void scatter_kernel(const int* __restrict__ row, const int* __restrict__ col,
                               const int* __restrict__ rank_local, const int* __restrict__ cntM,
                               const int* __restrict__ off, const float* __restrict__ nd,
                               int2* __restrict__ sedge, int* __restrict__ dstarr) {
    int e = blockIdx.x * 256 + threadIdx.x;
    int r = row[e], c = col[e];
    int ch = e / CHUNK;
    int p = off[c] + cntM[ch * N_NODES + c] + rank_local[e];
    int2 se;
    se.x = r;
    se.y = __float_as_int(nd[r] * nd[c]);
    sedge[p] = se;
    dstarr[p] = c;
}

// ---------------- input projection + fused y/z gate projections ----------------
__global__ __launch_bounds__(256) void proj_kernel(const float* __restrict__ x,
                                                   const float* __restrict__ W1,
                                                   const float* __restrict__ b1,
                                                   const float* __restrict__ gw,
                                                   float* __restrict__ ha,
                                                   ushort* __restrict__ habf,
                                                   float* __restrict__ y,
                                                   float* __restrict__ z) {
    __shared__ float xs[64 * ROWSZ];
    __shared__ float ws[64 * ROWSZ];
    int t = threadIdx.x;
    int nb = blockIdx.x * 64;
    int lane = t & 63, w = t >> 6;
    int l15 = lane & 15, g = lane >> 4;
    int hbase = 16 * w + 4 * g;
    float acc[4][4];
#pragma unroll
    for (int j = 0; j < 4; j++)
#pragma unroll
        for (int i = 0; i < 4; i++) acc[j][i] = 0.f;

    for (int kc = 0; kc < NFEAT; kc += 64) {
        __syncthreads();
#pragma unroll
        for (int i = 0; i < 4; i++) {
            int idx = t + 256 * i;
            int r_ = idx >> 4;
            int kq = idx & 15;
            int gn = nb + r_;
            float4 v = make_float4(0.f, 0.f, 0.f, 0.f);
            if (gn < N_NODES) v = *(const float4*)(x + (size_t)gn * NFEAT + kc + kq * 4);
            *(float4*)(xs + r_ * ROWSZ + kq * 4) = v;
            float4 wv = *(const float4*)(W1 + (size_t)r_ * NFEAT + kc + kq * 4);
            *(float4*)(ws + r_ * ROWSZ + kq * 4) = wv;
        }
        __syncthreads();
#pragma unroll 4
        for (int k = 0; k < 64; k += 4) {
            float4 a[4], b[4];
#pragma unroll
            for (int j = 0; j < 4; j++) a[j] = *(const float4*)(xs + (l15 + 16 * j) * ROWSZ + k);
#pragma unroll
            for (int i = 0; i < 4; i++) b[i] = *(const float4*)(ws + (hbase + i) * ROWSZ + k);
#pragma unroll
            for (int j = 0; j < 4; j++)
#pragma unroll
                for (int i = 0; i < 4; i++)
                    acc[j][i] += a[j].x * b[i].x + a[j].y * b[i].y + a[j].z * b[i].z + a[j].w * b[i].w;
        }
    }
    float4 bias = *(const float4*)(b1 + hbase);
    float4 wa4 = *(const float4*)(gw + hbase);
    float4 wb4 = *(const float4*)(gw + HID + hbase);
    int slot = w * 4 + g;  // 0..15
    __syncthreads();       // done with xs/ws tiles; reuse as y/z partial scratch
#pragma unroll
    for (int j = 0; j < 4; j++) {
        int gn = nb + l15 + 16 * j;
        float4 o;
        o.x = fmaxf(acc[j][0] + bias.x, 0.f);
        o.y = fmaxf(acc[j][1] + bias.y, 0.f);
        o.z = fmaxf(acc[j][2] + bias.z, 0.f);
        o.w = fmaxf(acc[j][3] + bias.w, 0.f);
        if (gn < N_NODES) {
            *(float4*)(ha + (size_t)gn * HID + hbase) = o;
            uint2 pk;
            pk.x = bf16rne2(o.x, o.y);
            pk.y = bf16rne2(o.z, o.w);
            *(uint2*)(habf + (size_t)gn * HID + hbase) = pk;
        }
        xs[(l15 + 16 * j) * 16 + slot] = o.x * wa4.x + o.y * wa4.y + o.z * wa4.z + o.w * wa4.w;
        ws[(l15 + 16 * j) * 16 + slot] = o.x * wb4.x + o.y * wb4.y + o.z * wb4.z + o.w * wb4.w;
    }
    __syncthreads();
    if (t < 64 && nb + t < N_NODES) {
        float sa = 0.f, sb = 0.f;
#pragma unroll
        for (int s = 0; s < 16; s++) { sa += xs[t * 16 + s]; sb += ws[t * 16 + s]; }
        y[nb + t] = sa;
        z[nb + t] = sb;
    }
}

// ---------------- edge-parallel gate precompute: gv = tanh(y[src]+z[dst]+gb)*nde --------
// One thread per CSR edge. sedge/dstarr/gedge coalesced; z[dst] run-coalesced (dst
// ascending); y[src] is the only random 4B gather. Removes tanh + y-gather from both
// agg inner loops (was computed 8x redundantly per edge inside the dependent chain).
// Pads gedge[E..E+32) with gv=0 sentinels so agg needs no index clamps.
__global__ void gate_kernel(const int2* __restrict__ sedge, const int* __restrict__ dstarr,
                            const float* __restrict__ yv, const float* __restrict__ zv,
                            const float* __restrict__ gb, int2* __restrict__ gedge) {
    int e = blockIdx.x * 256 + threadIdx.x;
    int2 se = sedge[e];
    int d = dstarr[e];
    float gv = fast_tanh(yv[se.x] + zv[d] + gb[0]) * __int_as_float(se.y);
    int2 g;
    g.x = se.x;
    g.y = __float_as_int(gv);
    gedge[e] = g;
    if (e < 32) {
        int2 zpad; zpad.x = 0; zpad.y = 0;
        gedge[N_EDGES + e] = zpad;
    }
}

// ---------------- CSR aggregation core: 8 edges/iter, bf16 gathers, 3-stage pipeline ----
// gv precomputed per edge (gedge = {src, gv}); inner loop is pure gather+FMA.
// Reads up to 31 entries past e1: within-CSR overreads have gv masked to 0 (cndmask),
// end-of-array overreads hit the 32-entry sentinel pad. Accumulation order unchanged.
__device__ __forceinline__ void agg_core8(const ushort* __restrict__ hbf,
                                          const int2* __restrict__ gedge,
                                          int e0, int e1, int q, int c8,
                                          float acc[8], float& gs_out) {
#pragma unroll
    for (int i = 0; i < 8; i++) acc[i] = 0.f;
    float gs = 0.f;
    if (e0 < e1) {
        int eA = e0 + q;
        int2 gA = gedge[eA];
        int eB = e0 + 8 + q;
        int2 gB = gedge[eB];
        int eC = e0 + 16 + q;
        int2 gC = gedge[eC];
        float gvA = (eA < e1) ? __int_as_float(gA.y) : 0.f;
        float gvB = (eB < e1) ? __int_as_float(gB.y) : 0.f;
        float gvC = (eC < e1) ? __int_as_float(gC.y) : 0.f;
        uint4 uA = *(const uint4*)(hbf + (size_t)gA.x * HID + c8);
        uint4 uB = *(const uint4*)(hbf + (size_t)gB.x * HID + c8);
        for (int base = e0; base < e1; base += 8) {
            // issue gather for group C (consumed 2 iterations from now)
            uint4 uC = *(const uint4*)(hbf + (size_t)gC.x * HID + c8);
            // gedge for group D (3 ahead); sentinel pad makes the read safe
            int eD = base + 24 + q;
            int2 gD = gedge[eD];
            float gvD = (eD < e1) ? __int_as_float(gD.y) : 0.f;
            // compute group A
            acc[0] += gvA * bflo(uA.x);
            acc[1] += gvA * bfhi(uA.x);
            acc[2] += gvA * bflo(uA.y);
            acc[3] += gvA * bfhi(uA.y);
            acc[4] += gvA * bflo(uA.z);
            acc[5] += gvA * bfhi(uA.z);
            acc[6] += gvA * bflo(uA.w);
            acc[7] += gvA * bfhi(uA.w);
            gs += gvA;
            // rotate pipeline registers
            gvA = gvB; uA = uB;
            gvB = gvC; uB = uC;
            gC = gD; gvC = gvD;
        }
    }
#pragma unroll
    for (int s = 8; s < 64; s <<= 1) {
#pragma unroll
        for (int i = 0; i < 8; i++) acc[i] += __shfl_xor(acc[i], s);
        gs += __shfl_xor(gs, s);
    }
    gs_out = gs;
}

// ---------------- layer 1 agg + fused y2/z2; writes bf16 hbbf only ----------------
__global__ void agg1_kernel(const float* __restrict__ ha, const ushort* __restrict__ habf,
                            const int2* __restrict__ gedge, const int* __restrict__ off,
                            const float* __restrict__ invcnt,
                            const float* __restrict__ gw2, ushort* __restrict__ hbbf,
                            float* __restrict__ y2, float* __restrict__ z2) {
    int t = threadIdx.x;
    int lane = t & 63;
    int node = blockIdx.x * 4 + (t >> 6);
    int q = lane >> 3, c8 = (lane & 7) * 8;
    float4 ra = *(const float4*)(ha + (size_t)node * HID + c8);
    float4 rb = *(const float4*)(ha + (size_t)node * HID + c8 + 4);
    float raw8[8] = {ra.x, ra.y, ra.z, ra.w, rb.x, rb.y, rb.z, rb.w};
    float acc[8]; float gs;
    agg_core8(habf, gedge, off[node], off[node + 1], q, c8, acc, gs);
    float invc = invcnt[node];
    float o[8];
#pragma unroll
    for (int i = 0; i < 8; i++) o[i] = EPS_RES * raw8[i] + (acc[i] + gs * raw8[i]) * invc;
    if (q == 0) {
        uint4 pk;
        pk.x = bf16rne2(o[0], o[1]);
        pk.y = bf16rne2(o[2], o[3]);
        pk.z = bf16rne2(o[4], o[5]);
        pk.w = bf16rne2(o[6], o[7]);
        *(uint4*)(hbbf + (size_t)node * HID + c8) = pk;
    }
    float4 wa0 = *(const float4*)(gw2 + c8);
    float4 wa1 = *(const float4*)(gw2 + c8 + 4);
    float4 wb0 = *(const float4*)(gw2 + HID + c8);
    float4 wb1 = *(const float4*)(gw2 + HID + c8 + 4);
    float p = o[0] * wa0.x + o[1] * wa0.y + o[2] * wa0.z + o[3] * wa0.w
            + o[4] * wa1.x + o[5] * wa1.y + o[6] * wa1.z + o[7] * wa1.w;
    float qq = o[0] * wb0.x + o[1] * wb0.y + o[2] * wb0.z + o[3] * wb0.w
             + o[4] * wb1.x + o[5] * wb1.y + o[6] * wb1.z + o[7] * wb1.w;
#pragma unroll
    for (int s = 1; s < 8; s <<= 1) { p += __shfl_xor(p, s); qq += __shfl_xor(qq, s); }
    if (lane == 0) { y2[node] = p; z2[node] = qq; }
}

// ---------------- layer 2 agg + classifier + log_softmax ----------------
__global__ void agg2_kernel(const ushort* __restrict__ hbbf, const float* __restrict__ ha,
                            const int2* __restrict__ gedge, const int* __restrict__ off,
                            const float* __restrict__ invcnt,
                            const float* __restrict__ W2, const float* __restrict__ b2,
                            float* __restrict__ out) {
    __shared__ float w2s[64 * 68];  // rows >= NCLS uninitialized; dead lanes discard
    __shared__ float b2s[NCLS];
    int t = threadIdx.x;
    for (int i = t; i < NCLS * HID; i += 256) w2s[(i >> 6) * 68 + (i & 63)] = W2[i];
    if (t < NCLS) b2s[t] = b2[t];
    int lane = t & 63;
    int wv = t >> 6;
    int node = blockIdx.x * 4 + wv;
    int q = lane >> 3, c8 = (lane & 7) * 8;
    uint4 hc = *(const uint4*)(hbbf + (size_t)node * HID + c8);
    float hcv[8] = {bflo(hc.x), bfhi(hc.x), bflo(hc.y), bfhi(hc.y),
                    bflo(hc.z), bfhi(hc.z), bflo(hc.w), bfhi(hc.w)};
    float4 ra = *(const float4*)(ha + (size_t)node * HID + c8);
    float4 rb = *(const float4*)(ha + (size_t)node * HID + c8 + 4);
    float raw8[8] = {ra.x, ra.y, ra.z, ra.w, rb.x, rb.y, rb.z, rb.w};
    float acc[8]; float gs;
    agg_core8(hbbf, gedge, off[node], off[node + 1], q, c8, acc, gs);
    float invc = invcnt[node];
    float o[8];
#pragma unroll
    for (int i = 0; i < 8; i++) o[i] = EPS_RES * raw8[i] + (acc[i] + gs * hcv[i]) * invc;
    __syncthreads();  // w2s ready (staged in parallel with the agg loop)
    float logit = 0.f;
    const float* wr = w2s + lane * 68;
#pragma unroll
    for (int g = 0; g < 8; g++) {
        float4 w0 = *(const float4*)(wr + g * 8);
        float4 w1 = *(const float4*)(wr + g * 8 + 4);
        // h[g*8+i] lives in lane g (its lane&7 == g channel group), element o[i]
        logit += w0.x * __int_as_float(__builtin_amdgcn_readlane(__float_as_int(o[0]), g))
               + w0.y * __int_as_float(__builtin_amdgcn_readlane(__float_as_int(o[1]), g))
               + w0.z * __int_as_float(__builtin_amdgcn_readlane(__float_as_int(o[2]), g))
               + w0.w * __int_as_float(__builtin_amdgcn_readlane(__float_as_int(o[3]), g))
               + w1.x * __int_as_float(__builtin_amdgcn_readlane(__float_as_int(o[4]), g))
               + w1.y * __int_as_float(__builtin_amdgcn_readlane(__float_as_int(o[5]), g))
               + w1.z * __int_as_float(__builtin_amdgcn_readlane(__float_as_int(o[6]), g))
               + w1.w * __int_as_float(__builtin_amdgcn_readlane(__float_as_int(o[7]), g));
    }
    if (lane < NCLS) logit += b2s[lane];
    float v = (lane < NCLS) ? logit : -INFINITY;
#pragma unroll
    for (int s = 1; s < 64; s <<= 1) v = fmaxf(v, __shfl_xor(v, s));
    float ex = (lane < NCLS) ? expf(logit - v) : 0.f;
#pragma unroll
    for (int s = 1; s < 64; s <<= 1) ex += __shfl_xor(ex, s);
    float ls = v + logf(ex);
    if (lane < NCLS) out[node * NCLS + lane] = logit - ls;
}

extern "C" void kernel_launch(void* const* d_in, const int* in_sizes, int n_in,
                              void* d_out, int out_size, void* d_ws, size_t ws_size,
                              hipStream_t stream) {
    const float* x  = (const float*)d_in[0];
    const int*   ei = (const int*)d_in[1];
    const float* W1 = (const float*)d_in[2];
    const float* b1 = (const float*)d_in[3];
    const float* W2 = (const float*)d_in[4];
    const float* b2 = (const float*)d_in[5];
    const float* gw = (const float*)d_in[6];
    const float* gb = (const float*)d_in[7];
    float* out = (float*)d_out;

    // ws layout (4B words): [sedge 2E][nd N][invcnt N][y N][z N][y2 N][z2 N]
    //   [ha 64N][habf 32N][hbbf 32N][off N+1][bsum 196][dstarr E][gedge 2E+64]
    // degM/cntM (EB*N each) alias ha; rank_local (E) aliases habf.
    // All consumed by scatter before proj writes ha/habf (launch order). ~43.3 MB.
    int2*  sedge  = (int2*)d_ws;
    float* nd     = (float*)(sedge + N_EDGES);
    float* invcnt = nd + N_NODES;
    float* y      = invcnt + N_NODES;
    float* z      = y + N_NODES;
    float* y2     = z + N_NODES;
    float* z2     = y2 + N_NODES;
    float* ha     = z2 + N_NODES;
    ushort* habf  = (ushort*)(ha + (size_t)N_NODES * HID);
    ushort* hbbf  = habf + (size_t)N_NODES * HID;
    int*   off    = (int*)(hbbf + (size_t)N_NODES * HID);
    int*   bsum   = off + N_NODES + 1;
    int*   dstarr = bsum + 256;
    int2*  gedge  = (int2*)(dstarr + N_EDGES);  // E+32 entries
    int*   degM   = (int*)ha;                  // EB*N ints
    int*   cntM   = degM + (size_t)EB * N_NODES;  // EB*N ints (both inside ha's 64N)
    int*   rank_local = (int*)habf;            // E ints <= 32N words

    const int* row = ei;
    const int* col = ei + N_EDGES;

    hist_kernel<<<dim3(EB, NR, 2), 256, 0, stream>>>(row, col, degM, cntM, rank_local);
    scan1_kernel<<<SCAN_BLOCKS, 256, 0, stream>>>(degM, cntM, off, bsum, nd, invcnt);
    scan2_kernel<<<1, 256, 0, stream>>>(bsum);
    scan3_kernel<<<SCAN_BLOCKS, 256, 0, stream>>>(off, bsum);
    scatter_kernel<<<N_EDGES / 256, 256, 0, stream>>>(row, col, rank_local, cntM, off, nd,
                                                      sedge, dstarr);
    proj_kernel<<<(N_NODES + 63) / 64, 256, 0, stream>>>(x, W1, b1, gw, ha, habf, y, z);

    gate_kernel<<<N_EDGES / 256, 256, 0, stream>>>(sedge, dstarr, y, z, gb, gedge);
    agg1_kernel<<<N_NODES / 4, 256, 0, stream>>>(ha, habf, gedge, off, invcnt,
                                                 gw + 2 * HID, hbbf, y2, z2);
    gate_kernel<<<N_EDGES / 256, 256, 0, stream>>>(sedge, dstarr, y2, z2, gb + 1, gedge);
    agg2_kernel<<<N_NODES / 4, 256, 0, stream>>>(hbbf, ha, gedge, off, invcnt,
                                                 W2, b2, out);
}

// Round 4
// 235.263 us; speedup vs baseline: 1.1964x; 1.1964x over previous
//
#include <hip/hip_runtime.h>
#include <math.h>

#define N_NODES 50000
#define N_EDGES 800000
#define NFEAT 256
#define HID 64
#define NCLS 40
#define EPS_RES 0.3f
#define ROWSZ 68  // LDS row pitch for proj (64 + 4 pad)
#define SCAN_BLOCKS ((N_NODES + 255) / 256)  // 196
#define EB 32                 // edge chunks
#define CHUNK (N_EDGES / EB)  // 25000
#define NR 4                  // node ranges
#define RNG (N_NODES / NR)    // 12500 -> 50KB LDS histogram

typedef unsigned int uint;
typedef unsigned short ushort;

__device__ __forceinline__ float bflo(uint u) { return __uint_as_float(u << 16); }
__device__ __forceinline__ float bfhi(uint u) { return __uint_as_float(u & 0xFFFF0000u); }
__device__ __forceinline__ uint bf16rne(float f) {
    uint u = __float_as_uint(f);
    return (u + 0x7FFFu + ((u >> 16) & 1u)) >> 16;
}
__device__ __forceinline__ uint bf16rne2(float a, float b) {
    return bf16rne(a) | (bf16rne(b) << 16);
}

// tanh(x) = 1 - 2/(e^{2x}+1) via v_exp_f32 + v_rcp_f32 (~2 ulp; exact +-1 limits).
__device__ __forceinline__ float fast_tanh(float x) {
    float t = __builtin_amdgcn_exp2f(x * 2.885390081777927f);  // e^{2x}
    return 1.0f - 2.0f * __builtin_amdgcn_rcpf(t + 1.0f);
}

// ---------------- degree histograms via LDS binning: ZERO global atomics ----------------
__global__ __launch_bounds__(256) void hist_kernel(const int* __restrict__ row,
                                                   const int* __restrict__ col,
                                                   int* __restrict__ degM,
                                                   int* __restrict__ cntM,
                                                   int* __restrict__ rank_local) {
    __shared__ int hist[RNG];
    int t = threadIdx.x;
    int chunk = blockIdx.x;
    int lo = blockIdx.y * RNG;
    int side = blockIdx.z;
    for (int j = t; j < RNG; j += 256) hist[j] = 0;
    __syncthreads();
    const int* idx = side ? col : row;
    int e0 = chunk * CHUNK;
    if (side == 0) {
        for (int base = 0; base < CHUNK; base += 1024) {
            int vb[4];
#pragma unroll
            for (int j = 0; j < 4; j++) {
                int i = base + j * 256 + t;
                vb[j] = (i < CHUNK) ? idx[e0 + i] : -1;
            }
#pragma unroll
            for (int j = 0; j < 4; j++) {
                uint v = (uint)(vb[j] - lo);
                if (v < RNG) atomicAdd(&hist[v], 1);
            }
        }
    } else {
        for (int base = 0; base < CHUNK; base += 1024) {
            int vb[4], ib[4];
#pragma unroll
            for (int j = 0; j < 4; j++) {
                int i = base + j * 256 + t;
                ib[j] = i;
                vb[j] = (i < CHUNK) ? idx[e0 + i] : -1;
            }
#pragma unroll
            for (int j = 0; j < 4; j++) {
                uint v = (uint)(vb[j] - lo);
                if (v < RNG) rank_local[e0 + ib[j]] = atomicAdd(&hist[v], 1);
            }
        }
    }
    __syncthreads();
    int* M = side ? cntM : degM;
    for (int j = t; j < RNG; j += 256) M[chunk * N_NODES + lo + j] = hist[j];
}

// ---------------- scan1: chunk-reduce (nd/invcnt + in-place cntM bases) + block scan ----
__device__ __forceinline__ int block_excl_scan_256(int v, int t, int* wsum) {
    int lane = t & 63, w = t >> 6;
    int sv = v;
#pragma unroll
    for (int d = 1; d < 64; d <<= 1) {
        int o = __shfl_up(sv, d);
        if (lane >= d) sv += o;
    }
    if (lane == 63) wsum[w] = sv;
    __syncthreads();
    int add = 0;
    for (int i = 0; i < w; i++) add += wsum[i];
    return sv + add - v;
}

__global__ void scan1_kernel(const int* __restrict__ degM, int* __restrict__ cntM,
                             int* __restrict__ off, int* __restrict__ bsum,
                             float* __restrict__ nd, float* __restrict__ invcnt) {
    __shared__ int wsum[4];
    int t = threadIdx.x;
    int idx = blockIdx.x * 256 + t;
    int v = 0;
    if (idx < N_NODES) {
        int sD = 0;
#pragma unroll
        for (int c = 0; c < EB; c++) sD += degM[c * N_NODES + idx];
        int run = 0;
#pragma unroll
        for (int c = 0; c < EB; c++) {
            int cv = cntM[c * N_NODES + idx];
            cntM[c * N_NODES + idx] = run;  // exclusive base for this chunk within bucket
            run += cv;
        }
        v = run;
        if (sD < 1) sD = 1;
        nd[idx] = rsqrtf((float)sD);
        int cc = run; if (cc < 1) cc = 1;
        invcnt[idx] = 1.0f / (float)cc;
    }
    int excl = block_excl_scan_256(v, t, wsum);
    if (idx < N_NODES) off[idx] = excl;
    if (t == 255) bsum[blockIdx.x] = excl + v;
}

__global__ void scan2_kernel(int* __restrict__ bsum) {
    __shared__ int wsum[4];
    int t = threadIdx.x;
    int v = (t < SCAN_BLOCKS) ? bsum[t] : 0;
    int excl = block_excl_scan_256(v, t, wsum);
    if (t < SCAN_BLOCKS) bsum[t] = excl;
}

__global__ void scan3_kernel(int* __restrict__ off, const int* __restrict__ bsum) {
    int t = threadIdx.x;
    int idx = blockIdx.x * 256 + t;
    if (idx < N_NODES) off[idx] += bsum[blockIdx.x];
    if (idx == 0) off[N_NODES] = N_EDGES;
}

// ---------------- CSR scatter: atomic-free, one 8B store per edge ----------------
__global__ void scatter_kernel(const int* __restrict__ row, const int* __restrict__ col,
                               const int* __restrict__ rank_local, const int* __restrict__ cntM,
                               const int* __restrict__ off, const float* __restrict__ nd,
                               int2* __restrict__ sedge) {
    int e = blockIdx.x * 256 + threadIdx.x;
    int r = row[e], c = col[e];
    int ch = e / CHUNK;
    int p = off[c] + cntM[ch * N_NODES + c] + rank_local[e];
    int2 se;
    se.x = r;
    se.y = __float_as_int(nd[r] * nd[c]);
    sedge[p] = se;
}

// ---------------- input projection + fused y/z gate projections ----------------
__global__ __launch_bounds__(256) void proj_kernel(const float* __restrict__ x,
                                                   const float* __restrict__ W1,
                                                   const float* __restrict__ b1,
                                                   const float* __restrict__ gw,
                                                   float* __restrict__ ha,
                                                   ushort* __restrict__ habf,
                                                   float* __restrict__ y,
                                                   float* __restrict__ z) {
    __shared__ float xs[64 * ROWSZ];
    __shared__ float ws[64 * ROWSZ];
    int t = threadIdx.x;
    int nb = blockIdx.x * 64;
    int lane = t & 63, w = t >> 6;
    int l15 = lane & 15, g = lane >> 4;
    int hbase = 16 * w + 4 * g;
    float acc[4][4];
#pragma unroll
    for (int j = 0; j < 4; j++)
#pragma unroll
        for (int i = 0; i < 4; i++) acc[j][i] = 0.f;

    for (int kc = 0; kc < NFEAT; kc += 64) {
        __syncthreads();
#pragma unroll
        for (int i = 0; i < 4; i++) {
            int idx = t + 256 * i;
            int r_ = idx >> 4;
            int kq = idx & 15;
            int gn = nb + r_;
            float4 v = make_float4(0.f, 0.f, 0.f, 0.f);
            if (gn < N_NODES) v = *(const float4*)(x + (size_t)gn * NFEAT + kc + kq * 4);
            *(float4*)(xs + r_ * ROWSZ + kq * 4) = v;
            float4 wv = *(const float4*)(W1 + (size_t)r_ * NFEAT + kc + kq * 4);
            *(float4*)(ws + r_ * ROWSZ + kq * 4) = wv;
        }
        __syncthreads();
#pragma unroll 4
        for (int k = 0; k < 64; k += 4) {
            float4 a[4], b[4];
#pragma unroll
            for (int j = 0; j < 4; j++) a[j] = *(const float4*)(xs + (l15 + 16 * j) * ROWSZ + k);
#pragma unroll
            for (int i = 0; i < 4; i++) b[i] = *(const float4*)(ws + (hbase + i) * ROWSZ + k);
#pragma unroll
            for (int j = 0; j < 4; j++)
#pragma unroll
                for (int i = 0; i < 4; i++)
                    acc[j][i] += a[j].x * b[i].x + a[j].y * b[i].y + a[j].z * b[i].z + a[j].w * b[i].w;
        }
    }
    float4 bias = *(const float4*)(b1 + hbase);
    float4 wa4 = *(const float4*)(gw + hbase);
    float4 wb4 = *(const float4*)(gw + HID + hbase);
    int slot = w * 4 + g;  // 0..15
    __syncthreads();       // done with xs/ws tiles; reuse as y/z partial scratch
#pragma unroll
    for (int j = 0; j < 4; j++) {
        int gn = nb + l15 + 16 * j;
        float4 o;
        o.x = fmaxf(acc[j][0] + bias.x, 0.f);
        o.y = fmaxf(acc[j][1] + bias.y, 0.f);
        o.z = fmaxf(acc[j][2] + bias.z, 0.f);
        o.w = fmaxf(acc[j][3] + bias.w, 0.f);
        if (gn < N_NODES) {
            *(float4*)(ha + (size_t)gn * HID + hbase) = o;
            uint2 pk;
            pk.x = bf16rne2(o.x, o.y);
            pk.y = bf16rne2(o.z, o.w);
            *(uint2*)(habf + (size_t)gn * HID + hbase) = pk;
        }
        xs[(l15 + 16 * j) * 16 + slot] = o.x * wa4.x + o.y * wa4.y + o.z * wa4.z + o.w * wa4.w;
        ws[(l15 + 16 * j) * 16 + slot] = o.x * wb4.x + o.y * wb4.y + o.z * wb4.z + o.w * wb4.w;
    }
    __syncthreads();
    if (t < 64 && nb + t < N_NODES) {
        float sa = 0.f, sb = 0.f;
#pragma unroll
        for (int s = 0; s < 16; s++) { sa += xs[t * 16 + s]; sb += ws[t * 16 + s]; }
        y[nb + t] = sa;
        z[nb + t] = sb;
    }
}

// ---------------- group-per-node CSR aggregation core -----------------------------------
// Wave = 8 groups x 8 lanes; each group owns ONE node's full edge list (1 edge per
// group per iteration -> 8 edges/wave/iter, identical 8x128B gather pattern to the
// old scheme). Each lane exclusively owns 8 channels of its node, so there is NO
// cross-lane accumulator reduce (was 27 ds_bpermute/node), gs is group-replicated,
// and one pipeline prologue serves 8 nodes. Loop trip = max degree over the wave's
// 8 groups (uniform, via 3-stage shfl max). Invalid slots clamp to edge 0 with
// nde=0 so no bounds pads are needed. Accumulation is sequential in CSR order.
__device__ __forceinline__ void agg_group8(const ushort* __restrict__ hbf,
                                           const int2* __restrict__ sedge,
                                           const float* __restrict__ yv,
                                           float zc, int e0, int d, int c8,
                                           float acc[8], float& gs_out) {
#pragma unroll
    for (int i = 0; i < 8; i++) acc[i] = 0.f;
    float gs = 0.f;
    int m = d;
    m = max(m, __shfl_xor(m, 8));
    m = max(m, __shfl_xor(m, 16));
    m = max(m, __shfl_xor(m, 32));
    if (m > 0) {
        int2 seA = sedge[(0 < d) ? e0 : 0];
        float ndeA = (0 < d) ? __int_as_float(seA.y) : 0.f;
        int2 seB = sedge[(1 < d) ? e0 + 1 : 0];
        float ndeB = (1 < d) ? __int_as_float(seB.y) : 0.f;
        int2 seC = sedge[(2 < d) ? e0 + 2 : 0];
        float ndeC = (2 < d) ? __int_as_float(seC.y) : 0.f;
        float yA = yv[seA.x];
        uint4 uA = *(const uint4*)(hbf + (size_t)seA.x * HID + c8);
        float yB = yv[seB.x];
        uint4 uB = *(const uint4*)(hbf + (size_t)seB.x * HID + c8);
        for (int k = 0; k < m; ++k) {
            // issue gathers for slot C (consumed 2 iterations from now)
            float yC = yv[seC.x];
            uint4 uC = *(const uint4*)(hbf + (size_t)seC.x * HID + c8);
            // sedge for slot D (3 ahead); clamp keeps the read in-bounds
            int kD = k + 3;
            int2 seD = sedge[(kD < d) ? e0 + kD : 0];
            float ndeD = (kD < d) ? __int_as_float(seD.y) : 0.f;
            // compute slot A (nde=0 kills invalid slots)
            float gv = fast_tanh(yA + zc) * ndeA;
            acc[0] += gv * bflo(uA.x);
            acc[1] += gv * bfhi(uA.x);
            acc[2] += gv * bflo(uA.y);
            acc[3] += gv * bfhi(uA.y);
            acc[4] += gv * bflo(uA.z);
            acc[5] += gv * bfhi(uA.z);
            acc[6] += gv * bflo(uA.w);
            acc[7] += gv * bfhi(uA.w);
            gs += gv;
            // rotate pipeline registers
            yA = yB; uA = uB; ndeA = ndeB;
            yB = yC; uB = uC; ndeB = ndeC;
            seC = seD; ndeC = ndeD;
        }
    }
    gs_out = gs;
}

// ---------------- layer 1 agg + fused y2/z2; writes bf16 hbbf only ----------------
// 32 nodes per block (4 waves x 8 groups). No LDS, no __syncthreads: waves independent.
__global__ __launch_bounds__(256) void agg1_kernel(
        const float* __restrict__ ha, const ushort* __restrict__ habf,
        const int2* __restrict__ sedge, const int* __restrict__ off,
        const float* __restrict__ invcnt, const float* __restrict__ y,
        const float* __restrict__ z, const float* __restrict__ gb,
        const float* __restrict__ gw2, ushort* __restrict__ hbbf,
        float* __restrict__ y2, float* __restrict__ z2) {
    int t = threadIdx.x;
    int lane = t & 63;
    int ln = t >> 3;  // 0..31 local node
    int node = blockIdx.x * 32 + ln;
    int nc = (node < N_NODES) ? node : (N_NODES - 1);
    int c8 = (lane & 7) * 8;
    int e0 = off[nc];
    int e1 = off[nc + 1];
    int d = (node < N_NODES) ? (e1 - e0) : 0;
    float zc = z[nc] + gb[0];
    float acc[8]; float gs;
    agg_group8(habf, sedge, y, zc, e0, d, c8, acc, gs);
    float invc = invcnt[nc];
    float4 ra = *(const float4*)(ha + (size_t)nc * HID + c8);
    float4 rb = *(const float4*)(ha + (size_t)nc * HID + c8 + 4);
    float raw8[8] = {ra.x, ra.y, ra.z, ra.w, rb.x, rb.y, rb.z, rb.w};
    float o[8];
#pragma unroll
    for (int i = 0; i < 8; i++) o[i] = EPS_RES * raw8[i] + (acc[i] + gs * raw8[i]) * invc;
    if (node < N_NODES) {
        uint4 pk;
        pk.x = bf16rne2(o[0], o[1]);
        pk.y = bf16rne2(o[2], o[3]);
        pk.z = bf16rne2(o[4], o[5]);
        pk.w = bf16rne2(o[6], o[7]);
        *(uint4*)(hbbf + (size_t)nc * HID + c8) = pk;
    }
    float4 wa0 = *(const float4*)(gw2 + c8);
    float4 wa1 = *(const float4*)(gw2 + c8 + 4);
    float4 wb0 = *(const float4*)(gw2 + HID + c8);
    float4 wb1 = *(const float4*)(gw2 + HID + c8 + 4);
    float p = o[0] * wa0.x + o[1] * wa0.y + o[2] * wa0.z + o[3] * wa0.w
            + o[4] * wa1.x + o[5] * wa1.y + o[6] * wa1.z + o[7] * wa1.w;
    float qq = o[0] * wb0.x + o[1] * wb0.y + o[2] * wb0.z + o[3] * wb0.w
             + o[4] * wb1.x + o[5] * wb1.y + o[6] * wb1.z + o[7] * wb1.w;
#pragma unroll
    for (int s = 1; s < 8; s <<= 1) { p += __shfl_xor(p, s); qq += __shfl_xor(qq, s); }
    if ((lane & 7) == 0 && node < N_NODES) { y2[node] = p; z2[node] = qq; }
}

// ---------------- layer 2 agg + classifier + log_softmax ----------------
// Phase A: group-per-node agg -> o[8]/lane -> hs[32][72] LDS. Phase B: 8 threads per
// node, 5 classes each (5 independent fmac chains, no 64-deep serial chain); softmax
// via 3-stage 8-lane group reduce with HW exp2/log2. w2s staged during agg (pitch 72,
// 16B aligned; 2-way LDS aliasing only, which is free).
__global__ __launch_bounds__(256) void agg2_kernel(
        const ushort* __restrict__ hbbf, const float* __restrict__ ha,
        const int2* __restrict__ sedge, const int* __restrict__ off,
        const float* __restrict__ invcnt, const float* __restrict__ y2,
        const float* __restrict__ z2, const float* __restrict__ gb,
        const float* __restrict__ W2, const float* __restrict__ b2,
        float* __restrict__ out) {
    __shared__ float w2s[NCLS * 72];
    __shared__ float b2s[NCLS];
    __shared__ float hs[32 * 72];
    int t = threadIdx.x;
    for (int i = t; i < NCLS * HID; i += 256) w2s[(i >> 6) * 72 + (i & 63)] = W2[i];
    if (t < NCLS) b2s[t] = b2[t];
    int lane = t & 63;
    int ln = t >> 3;  // 0..31 local node
    int node = blockIdx.x * 32 + ln;
    int nc = (node < N_NODES) ? node : (N_NODES - 1);
    int c8 = (lane & 7) * 8;
    int e0 = off[nc];
    int e1 = off[nc + 1];
    int d = (node < N_NODES) ? (e1 - e0) : 0;
    float zc = z2[nc] + gb[0];
    float acc[8]; float gs;
    agg_group8(hbbf, sedge, y2, zc, e0, d, c8, acc, gs);
    float invc = invcnt[nc];
    uint4 hc = *(const uint4*)(hbbf + (size_t)nc * HID + c8);
    float hcv[8] = {bflo(hc.x), bfhi(hc.x), bflo(hc.y), bfhi(hc.y),
                    bflo(hc.z), bfhi(hc.z), bflo(hc.w), bfhi(hc.w)};
    float4 ra = *(const float4*)(ha + (size_t)nc * HID + c8);
    float4 rb = *(const float4*)(ha + (size_t)nc * HID + c8 + 4);
    float raw8[8] = {ra.x, ra.y, ra.z, ra.w, rb.x, rb.y, rb.z, rb.w};
    float4 o0, o1;
    o0.x = EPS_RES * raw8[0] + (acc[0] + gs * hcv[0]) * invc;
    o0.y = EPS_RES * raw8[1] + (acc[1] + gs * hcv[1]) * invc;
    o0.z = EPS_RES * raw8[2] + (acc[2] + gs * hcv[2]) * invc;
    o0.w = EPS_RES * raw8[3] + (acc[3] + gs * hcv[3]) * invc;
    o1.x = EPS_RES * raw8[4] + (acc[4] + gs * hcv[4]) * invc;
    o1.y = EPS_RES * raw8[5] + (acc[5] + gs * hcv[5]) * invc;
    o1.z = EPS_RES * raw8[6] + (acc[6] + gs * hcv[6]) * invc;
    o1.w = EPS_RES * raw8[7] + (acc[7] + gs * hcv[7]) * invc;
    *(float4*)(hs + ln * 72 + c8) = o0;
    *(float4*)(hs + ln * 72 + c8 + 4) = o1;
    __syncthreads();
    // phase B: thread = (node ln, class subset k5 + 8j, j<5) -> exactly 40 classes
    int k5 = t & 7;
    float lg[5];
#pragma unroll
    for (int j = 0; j < 5; j++) lg[j] = b2s[k5 + 8 * j];
    const float* hrow = hs + ln * 72;
#pragma unroll
    for (int j4 = 0; j4 < 16; j4++) {
        float4 h4 = *(const float4*)(hrow + j4 * 4);
#pragma unroll
        for (int j = 0; j < 5; j++) {
            float4 w4 = *(const float4*)(w2s + (k5 + 8 * j) * 72 + j4 * 4);
            lg[j] += h4.x * w4.x + h4.y * w4.y + h4.z * w4.z + h4.w * w4.w;
        }
    }
    float v = fmaxf(fmaxf(fmaxf(lg[0], lg[1]), fmaxf(lg[2], lg[3])), lg[4]);
    v = fmaxf(v, __shfl_xor(v, 1));
    v = fmaxf(v, __shfl_xor(v, 2));
    v = fmaxf(v, __shfl_xor(v, 4));
    float ex = 0.f;
#pragma unroll
    for (int j = 0; j < 5; j++) ex += __builtin_amdgcn_exp2f((lg[j] - v) * 1.44269504088896f);
    ex += __shfl_xor(ex, 1);
    ex += __shfl_xor(ex, 2);
    ex += __shfl_xor(ex, 4);
    float ls = v + __builtin_amdgcn_logf(ex) * 0.693147180559945f;
    if (node < N_NODES) {
#pragma unroll
        for (int j = 0; j < 5; j++) out[(size_t)node * NCLS + k5 + 8 * j] = lg[j] - ls;
    }
}

extern "C" void kernel_launch(void* const* d_in, const int* in_sizes, int n_in,
                              void* d_out, int out_size, void* d_ws, size_t ws_size,
                              hipStream_t stream) {
    const float* x  = (const float*)d_in[0];
    const int*   ei = (const int*)d_in[1];
    const float* W1 = (const float*)d_in[2];
    const float* b1 = (const float*)d_in[3];
    const float* W2 = (const float*)d_in[4];
    const float* b2 = (const float*)d_in[5];
    const float* gw = (const float*)d_in[6];
    const float* gb = (const float*)d_in[7];
    float* out = (float*)d_out;

    // ws layout (4B words): [sedge 2E][nd N][invcnt N][y N][z N][y2 N][z2 N]
    //   [ha 64N][habf 32N][hbbf 32N][off N+1][bsum 196]
    // degM/cntM (EB*N each = 12.8MB total) alias ha; rank_local (E) aliases habf.
    // All consumed by scatter before proj writes ha/habf (launch order). ~33.7 MB.
    int2*  sedge  = (int2*)d_ws;
    float* nd     = (float*)(sedge + N_EDGES);
    float* invcnt = nd + N_NODES;
    float* y      = invcnt + N_NODES;
    float* z      = y + N_NODES;
    float* y2     = z + N_NODES;
    float* z2     = y2 + N_NODES;
    float* ha     = z2 + N_NODES;
    ushort* habf  = (ushort*)(ha + (size_t)N_NODES * HID);
    ushort* hbbf  = habf + (size_t)N_NODES * HID;
    int*   off    = (int*)(hbbf + (size_t)N_NODES * HID);
    int*   bsum   = off + N_NODES + 1;
    int*   degM   = (int*)ha;                  // EB*N ints
    int*   cntM   = degM + (size_t)EB * N_NODES;  // EB*N ints (both inside ha's 64N)
    int*   rank_local = (int*)habf;            // E ints <= 32N words

    const int* row = ei;
    const int* col = ei + N_EDGES;

    hist_kernel<<<dim3(EB, NR, 2), 256, 0, stream>>>(row, col, degM, cntM, rank_local);
    scan1_kernel<<<SCAN_BLOCKS, 256, 0, stream>>>(degM, cntM, off, bsum, nd, invcnt);
    scan2_kernel<<<1, 256, 0, stream>>>(bsum);
    scan3_kernel<<<SCAN_BLOCKS, 256, 0, stream>>>(off, bsum);
    scatter_kernel<<<N_EDGES / 256, 256, 0, stream>>>(row, col, rank_local, cntM, off, nd, sedge);
    proj_kernel<<<(N_NODES + 63) / 64, 256, 0, stream>>>(x, W1, b1, gw, ha, habf, y, z);

    int aggblocks = (N_NODES + 31) / 32;  // 1563
    agg1_kernel<<<aggblocks, 256, 0, stream>>>(ha, habf, sedge, off, invcnt, y, z, gb,
                                               gw + 2 * HID, hbbf, y2, z2);
    agg2_kernel<<<aggblocks, 256, 0, stream>>>(hbbf, ha, sedge, off, invcnt, y2, z2,
                                               gb + 1, W2, b2, out);
}

// Round 5
// 220.869 us; speedup vs baseline: 1.2744x; 1.0652x over previous
//
#include <hip/hip_runtime.h>
#include <math.h>

#define N_NODES 50000
#define N_EDGES 800000
#define NFEAT 256
#define HID 64
#define NCLS 40
#define EPS_RES 0.3f
#define SCAN_BLOCKS ((N_NODES + 255) / 256)  // 196
#define EB 32                 // edge chunks
#define CHUNK (N_EDGES / EB)  // 25000
#define NR 4                  // node ranges
#define RNG (N_NODES / NR)    // 12500 -> 50KB LDS histogram

typedef unsigned int uint;
typedef unsigned short ushort;
typedef __attribute__((ext_vector_type(8))) short short8v;   // bf16x8 MFMA A/B frag
typedef __attribute__((ext_vector_type(4))) float f32x4;     // MFMA C/D frag

__device__ __forceinline__ float bflo(uint u) { return __uint_as_float(u << 16); }
__device__ __forceinline__ float bfhi(uint u) { return __uint_as_float(u & 0xFFFF0000u); }
__device__ __forceinline__ uint bf16rne(float f) {
    uint u = __float_as_uint(f);
    return (u + 0x7FFFu + ((u >> 16) & 1u)) >> 16;
}
__device__ __forceinline__ uint bf16rne2(float a, float b) {
    return bf16rne(a) | (bf16rne(b) << 16);
}

// exact fp32 -> bf16_hi + bf16_lo split (Dekker-style; hi+lo reproduces x to ~2^-18 rel)
__device__ __forceinline__ void bfsplit(float v, ushort& h, ushort& l) {
    uint hb_ = bf16rne(v);
    float hf = __uint_as_float(hb_ << 16);
    uint lb_ = bf16rne(v - hf);
    h = (ushort)hb_;
    l = (ushort)lb_;
}

// tanh(x) = 1 - 2/(e^{2x}+1) via v_exp_f32 + v_rcp_f32 (~2 ulp; exact +-1 limits).
__device__ __forceinline__ float fast_tanh(float x) {
    float t = __builtin_amdgcn_exp2f(x * 2.885390081777927f);  // e^{2x}
    return 1.0f - 2.0f * __builtin_amdgcn_rcpf(t + 1.0f);
}

// ---------------- degree histograms via LDS binning: ZERO global atomics ----------------
__global__ __launch_bounds__(256) void hist_kernel(const int* __restrict__ row,
                                                   const int* __restrict__ col,
                                                   int* __restrict__ degM,
                                                   int* __restrict__ cntM,
                                                   int* __restrict__ rank_local) {
    __shared__ int hist[RNG];
    int t = threadIdx.x;
    int chunk = blockIdx.x;
    int lo = blockIdx.y * RNG;
    int side = blockIdx.z;
    for (int j = t; j < RNG; j += 256) hist[j] = 0;
    __syncthreads();
    const int* idx = side ? col : row;
    int e0 = chunk * CHUNK;
    if (side == 0) {
        for (int base = 0; base < CHUNK; base += 1024) {
            int vb[4];
#pragma unroll
            for (int j = 0; j < 4; j++) {
                int i = base + j * 256 + t;
                vb[j] = (i < CHUNK) ? idx[e0 + i] : -1;
            }
#pragma unroll
            for (int j = 0; j < 4; j++) {
                uint v = (uint)(vb[j] - lo);
                if (v < RNG) atomicAdd(&hist[v], 1);
            }
        }
    } else {
        for (int base = 0; base < CHUNK; base += 1024) {
            int vb[4], ib[4];
#pragma unroll
            for (int j = 0; j < 4; j++) {
                int i = base + j * 256 + t;
                ib[j] = i;
                vb[j] = (i < CHUNK) ? idx[e0 + i] : -1;
            }
#pragma unroll
            for (int j = 0; j < 4; j++) {
                uint v = (uint)(vb[j] - lo);
                if (v < RNG) rank_local[e0 + ib[j]] = atomicAdd(&hist[v], 1);
            }
        }
    }
    __syncthreads();
    int* M = side ? cntM : degM;
    for (int j = t; j < RNG; j += 256) M[chunk * N_NODES + lo + j] = hist[j];
}

// ---------------- scan1: chunk-reduce (nd/invcnt + in-place cntM bases) + block scan ----
__device__ __forceinline__ int block_excl_scan_256(int v, int t, int* wsum) {
    int lane = t & 63, w = t >> 6;
    int sv = v;
#pragma unroll
    for (int d = 1; d < 64; d <<= 1) {
        int o = __shfl_up(sv, d);
        if (lane >= d) sv += o;
    }
    if (lane == 63) wsum[w] = sv;
    __syncthreads();
    int add = 0;
    for (int i = 0; i < w; i++) add += wsum[i];
    return sv + add - v;
}

__global__ void scan1_kernel(const int* __restrict__ degM, int* __restrict__ cntM,
                             int* __restrict__ off, int* __restrict__ bsum,
                             float* __restrict__ nd, float* __restrict__ invcnt) {
    __shared__ int wsum[4];
    int t = threadIdx.x;
    int idx = blockIdx.x * 256 + t;
    int v = 0;
    if (idx < N_NODES) {
        int sD = 0;
#pragma unroll
        for (int c = 0; c < EB; c++) sD += degM[c * N_NODES + idx];
        int run = 0;
#pragma unroll
        for (int c = 0; c < EB; c++) {
            int cv = cntM[c * N_NODES + idx];
            cntM[c * N_NODES + idx] = run;  // exclusive base for this chunk within bucket
            run += cv;
        }
        v = run;
        if (sD < 1) sD = 1;
        nd[idx] = rsqrtf((float)sD);
        int cc = run; if (cc < 1) cc = 1;
        invcnt[idx] = 1.0f / (float)cc;
    }
    int excl = block_excl_scan_256(v, t, wsum);
    if (idx < N_NODES) off[idx] = excl;
    if (t == 255) bsum[blockIdx.x] = excl + v;
}

__global__ void scan2_kernel(int* __restrict__ bsum) {
    __shared__ int wsum[4];
    int t = threadIdx.x;
    int v = (t < SCAN_BLOCKS) ? bsum[t] : 0;
    int excl = block_excl_scan_256(v, t, wsum);
    if (t < SCAN_BLOCKS) bsum[t] = excl;
}

__global__ void scan3_kernel(int* __restrict__ off, const int* __restrict__ bsum) {
    int t = threadIdx.x;
    int idx = blockIdx.x * 256 + t;
    if (idx < N_NODES) off[idx] += bsum[blockIdx.x];
    if (idx == 0) off[N_NODES] = N_EDGES;
}

// ---------------- CSR scatter: atomic-free, one 8B store per edge ----------------
__global__ void scatter_kernel(const int* __restrict__ row, const int* __restrict__ col,
                               const int* __restrict__ rank_local, const int* __restrict__ cntM,
                               const int* __restrict__ off, const float* __restrict__ nd,
                               int2* __restrict__ sedge) {
    int e = blockIdx.x * 256 + threadIdx.x;
    int r = row[e], c = col[e];
    int ch = e / CHUNK;
    int p = off[c] + cntM[ch * N_NODES + c] + rank_local[e];
    int2 se;
    se.x = r;
    se.y = __float_as_int(nd[r] * nd[c]);
    sedge[p] = se;
}

// ---------------- input projection via MFMA bf16x3 (error-free split) -------------------
// H = X @ W1^T with X,W1 split into hi/lo bf16: h = xh*wh + xh*wl + xl*wh (xl*wl ~2^-18,
// dropped). 64-node x 64-hid tile, 4 waves; wave w computes nodes [w*16,w*16+16) x all
// 64 hid via mfma_f32_16x16x32_bf16 (A row=lane&15, K-octet=lane>>4; D col=lane&15,
// row=(lane>>4)*4+reg). LDS pitch 72 shorts (144B) -> 2-way bank aliasing only (free).
// Epilogue bounces acc through LDS to reuse the coalesced ha/habf/y/z write path.
__global__ __launch_bounds__(256) void proj_kernel(const float* __restrict__ x,
                                                   const float* __restrict__ W1,
                                                   const float* __restrict__ b1,
                                                   const float* __restrict__ gw,
                                                   float* __restrict__ ha,
                                                   ushort* __restrict__ habf,
                                                   float* __restrict__ y,
                                                   float* __restrict__ z) {
    __shared__ ushort smem[4 * 64 * 72];  // 36,864 B
    ushort* xs_h = smem;
    ushort* xs_l = smem + 4608;
    ushort* ws_h = smem + 9216;
    ushort* ws_l = smem + 13824;
    int t = threadIdx.x;
    int nb = blockIdx.x * 64;
    int lane = t & 63, w = t >> 6;
    int l15 = lane & 15, g = lane >> 4;
    int hbase = 16 * w + 4 * g;

    f32x4 acc[4];
#pragma unroll
    for (int hb = 0; hb < 4; hb++) acc[hb] = (f32x4)0.f;

    for (int kc = 0; kc < NFEAT; kc += 64) {
        __syncthreads();
#pragma unroll
        for (int i = 0; i < 4; i++) {
            int idx = t + 256 * i;
            int r_ = idx >> 4;     // 0..63 row (node-local for X, hid for W)
            int kq = idx & 15;     // float4 slot in the 64-wide K chunk
            int gn = nb + r_;
            float4 v = make_float4(0.f, 0.f, 0.f, 0.f);
            if (gn < N_NODES) v = *(const float4*)(x + (size_t)gn * NFEAT + kc + kq * 4);
            ushort4 h4, l4;
            bfsplit(v.x, h4.x, l4.x);
            bfsplit(v.y, h4.y, l4.y);
            bfsplit(v.z, h4.z, l4.z);
            bfsplit(v.w, h4.w, l4.w);
            *(ushort4*)(xs_h + r_ * 72 + kq * 4) = h4;
            *(ushort4*)(xs_l + r_ * 72 + kq * 4) = l4;
            float4 wv = *(const float4*)(W1 + (size_t)r_ * NFEAT + kc + kq * 4);
            bfsplit(wv.x, h4.x, l4.x);
            bfsplit(wv.y, h4.y, l4.y);
            bfsplit(wv.z, h4.z, l4.z);
            bfsplit(wv.w, h4.w, l4.w);
            *(ushort4*)(ws_h + r_ * 72 + kq * 4) = h4;
            *(ushort4*)(ws_l + r_ * 72 + kq * 4) = l4;
        }
        __syncthreads();
#pragma unroll
        for (int ko = 0; ko < 2; ko++) {
            int koff = ko * 32 + g * 8;  // K-octet for this lane
            short8v a_h = *(const short8v*)(xs_h + (w * 16 + l15) * 72 + koff);
            short8v a_l = *(const short8v*)(xs_l + (w * 16 + l15) * 72 + koff);
            short8v b_h[4], b_l[4];
#pragma unroll
            for (int hb = 0; hb < 4; hb++) {
                b_h[hb] = *(const short8v*)(ws_h + (hb * 16 + l15) * 72 + koff);
                b_l[hb] = *(const short8v*)(ws_l + (hb * 16 + l15) * 72 + koff);
            }
#pragma unroll
            for (int hb = 0; hb < 4; hb++) {
                acc[hb] = __builtin_amdgcn_mfma_f32_16x16x32_bf16(a_h, b_h[hb], acc[hb], 0, 0, 0);
                acc[hb] = __builtin_amdgcn_mfma_f32_16x16x32_bf16(a_h, b_l[hb], acc[hb], 0, 0, 0);
                acc[hb] = __builtin_amdgcn_mfma_f32_16x16x32_bf16(a_l, b_h[hb], acc[hb], 0, 0, 0);
            }
        }
    }
    // ---- epilogue: acc -> LDS (node-major) -> coalesced stores + y/z partials ----
    __syncthreads();
    float* hsf = (float*)smem;            // [64][68] fp32, 17,408 B
    float* ypart = hsf + 64 * 68;         // [64][16]
    float* zpart = ypart + 1024;          // [64][16]
#pragma unroll
    for (int hb = 0; hb < 4; hb++)
#pragma unroll
        for (int r = 0; r < 4; r++) {
            int nl = w * 16 + g * 4 + r;          // node-local row
            hsf[nl * 68 + hb * 16 + l15] = acc[hb][r];
        }
    __syncthreads();
    float4 bias = *(const float4*)(b1 + hbase);
    float4 wa4 = *(const float4*)(gw + hbase);
    float4 wb4 = *(const float4*)(gw + HID + hbase);
    int slot = w * 4 + g;  // 0..15
#pragma unroll
    for (int j = 0; j < 4; j++) {
        int rowl = l15 + 16 * j;
        int gn = nb + rowl;
        float4 hv = *(const float4*)(hsf + rowl * 68 + hbase);
        float4 o;
        o.x = fmaxf(hv.x + bias.x, 0.f);
        o.y = fmaxf(hv.y + bias.y, 0.f);
        o.z = fmaxf(hv.z + bias.z, 0.f);
        o.w = fmaxf(hv.w + bias.w, 0.f);
        if (gn < N_NODES) {
            *(float4*)(ha + (size_t)gn * HID + hbase) = o;
            uint2 pk;
            pk.x = bf16rne2(o.x, o.y);
            pk.y = bf16rne2(o.z, o.w);
            *(uint2*)(habf + (size_t)gn * HID + hbase) = pk;
        }
        ypart[rowl * 16 + slot] = o.x * wa4.x + o.y * wa4.y + o.z * wa4.z + o.w * wa4.w;
        zpart[rowl * 16 + slot] = o.x * wb4.x + o.y * wb4.y + o.z * wb4.z + o.w * wb4.w;
    }
    __syncthreads();
    if (t < 64 && nb + t < N_NODES) {
        float sa = 0.f, sb = 0.f;
#pragma unroll
        for (int s = 0; s < 16; s++) { sa += ypart[t * 16 + s]; sb += zpart[t * 16 + s]; }
        y[nb + t] = sa;
        z[nb + t] = sb;
    }
}

// ---------------- group-per-node CSR aggregation core -----------------------------------
// Wave = 8 groups x 8 lanes; each group owns ONE node's full edge list (1 edge per
// group per iteration -> 8 edges/wave/iter). Each lane exclusively owns 8 channels of
// its node: no cross-lane accumulator reduce, gs group-replicated, one prologue per
// 8 nodes. Loop trip = max degree over the wave's 8 groups. Invalid slots clamp to
// edge 0 with nde=0. Accumulation is sequential in CSR order.
__device__ __forceinline__ void agg_group8(const ushort* __restrict__ hbf,
                                           const int2* __restrict__ sedge,
                                           const float* __restrict__ yv,
                                           float zc, int e0, int d, int c8,
                                           float acc[8], float& gs_out) {
#pragma unroll
    for (int i = 0; i < 8; i++) acc[i] = 0.f;
    float gs = 0.f;
    int m = d;
    m = max(m, __shfl_xor(m, 8));
    m = max(m, __shfl_xor(m, 16));
    m = max(m, __shfl_xor(m, 32));
    if (m > 0) {
        int2 seA = sedge[(0 < d) ? e0 : 0];
        float ndeA = (0 < d) ? __int_as_float(seA.y) : 0.f;
        int2 seB = sedge[(1 < d) ? e0 + 1 : 0];
        float ndeB = (1 < d) ? __int_as_float(seB.y) : 0.f;
        int2 seC = sedge[(2 < d) ? e0 + 2 : 0];
        float ndeC = (2 < d) ? __int_as_float(seC.y) : 0.f;
        float yA = yv[seA.x];
        uint4 uA = *(const uint4*)(hbf + (size_t)seA.x * HID + c8);
        float yB = yv[seB.x];
        uint4 uB = *(const uint4*)(hbf + (size_t)seB.x * HID + c8);
        for (int k = 0; k < m; ++k) {
            float yC = yv[seC.x];
            uint4 uC = *(const uint4*)(hbf + (size_t)seC.x * HID + c8);
            int kD = k + 3;
            int2 seD = sedge[(kD < d) ? e0 + kD : 0];
            float ndeD = (kD < d) ? __int_as_float(seD.y) : 0.f;
            float gv = fast_tanh(yA + zc) * ndeA;
            acc[0] += gv * bflo(uA.x);
            acc[1] += gv * bfhi(uA.x);
            acc[2] += gv * bflo(uA.y);
            acc[3] += gv * bfhi(uA.y);
            acc[4] += gv * bflo(uA.z);
            acc[5] += gv * bfhi(uA.z);
            acc[6] += gv * bflo(uA.w);
            acc[7] += gv * bfhi(uA.w);
            gs += gv;
            yA = yB; uA = uB; ndeA = ndeB;
            yB = yC; uB = uC; ndeB = ndeC;
            seC = seD; ndeC = ndeD;
        }
    }
    gs_out = gs;
}

// ---------------- layer 1 agg + fused y2/z2; writes bf16 hbbf only ----------------
__global__ __launch_bounds__(256) void agg1_kernel(
        const float* __restrict__ ha, const ushort* __restrict__ habf,
        const int2* __restrict__ sedge, const int* __restrict__ off,
        const float* __restrict__ invcnt, const float* __restrict__ y,
        const float* __restrict__ z, const float* __restrict__ gb,
        const float* __restrict__ gw2, ushort* __restrict__ hbbf,
        float* __restrict__ y2, float* __restrict__ z2) {
    int t = threadIdx.x;
    int lane = t & 63;
    int ln = t >> 3;  // 0..31 local node
    int node = blockIdx.x * 32 + ln;
    int nc = (node < N_NODES) ? node : (N_NODES - 1);
    int c8 = (lane & 7) * 8;
    int e0 = off[nc];
    int e1 = off[nc + 1];
    int d = (node < N_NODES) ? (e1 - e0) : 0;
    float zc = z[nc] + gb[0];
    float acc[8]; float gs;
    agg_group8(habf, sedge, y, zc, e0, d, c8, acc, gs);
    float invc = invcnt[nc];
    float4 ra = *(const float4*)(ha + (size_t)nc * HID + c8);
    float4 rb = *(const float4*)(ha + (size_t)nc * HID + c8 + 4);
    float raw8[8] = {ra.x, ra.y, ra.z, ra.w, rb.x, rb.y, rb.z, rb.w};
    float o[8];
#pragma unroll
    for (int i = 0; i < 8; i++) o[i] = EPS_RES * raw8[i] + (acc[i] + gs * raw8[i]) * invc;
    if (node < N_NODES) {
        uint4 pk;
        pk.x = bf16rne2(o[0], o[1]);
        pk.y = bf16rne2(o[2], o[3]);
        pk.z = bf16rne2(o[4], o[5]);
        pk.w = bf16rne2(o[6], o[7]);
        *(uint4*)(hbbf + (size_t)nc * HID + c8) = pk;
    }
    float4 wa0 = *(const float4*)(gw2 + c8);
    float4 wa1 = *(const float4*)(gw2 + c8 + 4);
    float4 wb0 = *(const float4*)(gw2 + HID + c8);
    float4 wb1 = *(const float4*)(gw2 + HID + c8 + 4);
    float p = o[0] * wa0.x + o[1] * wa0.y + o[2] * wa0.z + o[3] * wa0.w
            + o[4] * wa1.x + o[5] * wa1.y + o[6] * wa1.z + o[7] * wa1.w;
    float qq = o[0] * wb0.x + o[1] * wb0.y + o[2] * wb0.z + o[3] * wb0.w
             + o[4] * wb1.x + o[5] * wb1.y + o[6] * wb1.z + o[7] * wb1.w;
#pragma unroll
    for (int s = 1; s < 8; s <<= 1) { p += __shfl_xor(p, s); qq += __shfl_xor(qq, s); }
    if ((lane & 7) == 0 && node < N_NODES) { y2[node] = p; z2[node] = qq; }
}

// ---------------- layer 2 agg + classifier + log_softmax ----------------
__global__ __launch_bounds__(256) void agg2_kernel(
        const ushort* __restrict__ hbbf, const float* __restrict__ ha,
        const int2* __restrict__ sedge, const int* __restrict__ off,
        const float* __restrict__ invcnt, const float* __restrict__ y2,
        const float* __restrict__ z2, const float* __restrict__ gb,
        const float* __restrict__ W2, const float* __restrict__ b2,
        float* __restrict__ out) {
    __shared__ float w2s[NCLS * 72];
    __shared__ float b2s[NCLS];
    __shared__ float hs[32 * 72];
    int t = threadIdx.x;
    for (int i = t; i < NCLS * HID; i += 256) w2s[(i >> 6) * 72 + (i & 63)] = W2[i];
    if (t < NCLS) b2s[t] = b2[t];
    int lane = t & 63;
    int ln = t >> 3;  // 0..31 local node
    int node = blockIdx.x * 32 + ln;
    int nc = (node < N_NODES) ? node : (N_NODES - 1);
    int c8 = (lane & 7) * 8;
    int e0 = off[nc];
    int e1 = off[nc + 1];
    int d = (node < N_NODES) ? (e1 - e0) : 0;
    float zc = z2[nc] + gb[0];
    float acc[8]; float gs;
    agg_group8(hbbf, sedge, y2, zc, e0, d, c8, acc, gs);
    float invc = invcnt[nc];
    uint4 hc = *(const uint4*)(hbbf + (size_t)nc * HID + c8);
    float hcv[8] = {bflo(hc.x), bfhi(hc.x), bflo(hc.y), bfhi(hc.y),
                    bflo(hc.z), bfhi(hc.z), bflo(hc.w), bfhi(hc.w)};
    float4 ra = *(const float4*)(ha + (size_t)nc * HID + c8);
    float4 rb = *(const float4*)(ha + (size_t)nc * HID + c8 + 4);
    float raw8[8] = {ra.x, ra.y, ra.z, ra.w, rb.x, rb.y, rb.z, rb.w};
    float4 o0, o1;
    o0.x = EPS_RES * raw8[0] + (acc[0] + gs * hcv[0]) * invc;
    o0.y = EPS_RES * raw8[1] + (acc[1] + gs * hcv[1]) * invc;
    o0.z = EPS_RES * raw8[2] + (acc[2] + gs * hcv[2]) * invc;
    o0.w = EPS_RES * raw8[3] + (acc[3] + gs * hcv[3]) * invc;
    o1.x = EPS_RES * raw8[4] + (acc[4] + gs * hcv[4]) * invc;
    o1.y = EPS_RES * raw8[5] + (acc[5] + gs * hcv[5]) * invc;
    o1.z = EPS_RES * raw8[6] + (acc[6] + gs * hcv[6]) * invc;
    o1.w = EPS_RES * raw8[7] + (acc[7] + gs * hcv[7]) * invc;
    *(float4*)(hs + ln * 72 + c8) = o0;
    *(float4*)(hs + ln * 72 + c8 + 4) = o1;
    __syncthreads();
    int k5 = t & 7;
    float lg[5];
#pragma unroll
    for (int j = 0; j < 5; j++) lg[j] = b2s[k5 + 8 * j];
    const float* hrow = hs + ln * 72;
#pragma unroll
    for (int j4 = 0; j4 < 16; j4++) {
        float4 h4 = *(const float4*)(hrow + j4 * 4);
#pragma unroll
        for (int j = 0; j < 5; j++) {
            float4 w4 = *(const float4*)(w2s + (k5 + 8 * j) * 72 + j4 * 4);
            lg[j] += h4.x * w4.x + h4.y * w4.y + h4.z * w4.z + h4.w * w4.w;
        }
    }
    float v = fmaxf(fmaxf(fmaxf(lg[0], lg[1]), fmaxf(lg[2], lg[3])), lg[4]);
    v = fmaxf(v, __shfl_xor(v, 1));
    v = fmaxf(v, __shfl_xor(v, 2));
    v = fmaxf(v, __shfl_xor(v, 4));
    float ex = 0.f;
#pragma unroll
    for (int j = 0; j < 5; j++) ex += __builtin_amdgcn_exp2f((lg[j] - v) * 1.44269504088896f);
    ex += __shfl_xor(ex, 1);
    ex += __shfl_xor(ex, 2);
    ex += __shfl_xor(ex, 4);
    float ls = v + __builtin_amdgcn_logf(ex) * 0.693147180559945f;
    if (node < N_NODES) {
#pragma unroll
        for (int j = 0; j < 5; j++) out[(size_t)node * NCLS + k5 + 8 * j] = lg[j] - ls;
    }
}

extern "C" void kernel_launch(void* const* d_in, const int* in_sizes, int n_in,
                              void* d_out, int out_size, void* d_ws, size_t ws_size,
                              hipStream_t stream) {
    const float* x  = (const float*)d_in[0];
    const int*   ei = (const int*)d_in[1];
    const float* W1 = (const float*)d_in[2];
    const float* b1 = (const float*)d_in[3];
    const float* W2 = (const float*)d_in[4];
    const float* b2 = (const float*)d_in[5];
    const float* gw = (const float*)d_in[6];
    const float* gb = (const float*)d_in[7];
    float* out = (float*)d_out;

    // ws layout (4B words): [sedge 2E][nd N][invcnt N][y N][z N][y2 N][z2 N]
    //   [ha 64N][habf 32N][hbbf 32N][off N+1][bsum 196]
    // degM/cntM (EB*N each = 12.8MB total) alias ha; rank_local (E) aliases habf.
    // All consumed by scatter before proj writes ha/habf (launch order). ~33.7 MB.
    int2*  sedge  = (int2*)d_ws;
    float* nd     = (float*)(sedge + N_EDGES);
    float* invcnt = nd + N_NODES;
    float* y      = invcnt + N_NODES;
    float* z      = y + N_NODES;
    float* y2     = z + N_NODES;
    float* z2     = y2 + N_NODES;
    float* ha     = z2 + N_NODES;
    ushort* habf  = (ushort*)(ha + (size_t)N_NODES * HID);
    ushort* hbbf  = habf + (size_t)N_NODES * HID;
    int*   off    = (int*)(hbbf + (size_t)N_NODES * HID);
    int*   bsum   = off + N_NODES + 1;
    int*   degM   = (int*)ha;                  // EB*N ints
    int*   cntM   = degM + (size_t)EB * N_NODES;  // EB*N ints (both inside ha's 64N)
    int*   rank_local = (int*)habf;            // E ints <= 32N words

    const int* row = ei;
    const int* col = ei + N_EDGES;

    hist_kernel<<<dim3(EB, NR, 2), 256, 0, stream>>>(row, col, degM, cntM, rank_local);
    scan1_kernel<<<SCAN_BLOCKS, 256, 0, stream>>>(degM, cntM, off, bsum, nd, invcnt);
    scan2_kernel<<<1, 256, 0, stream>>>(bsum);
    scan3_kernel<<<SCAN_BLOCKS, 256, 0, stream>>>(off, bsum);
    scatter_kernel<<<N_EDGES / 256, 256, 0, stream>>>(row, col, rank_local, cntM, off, nd, sedge);
    proj_kernel<<<(N_NODES + 63) / 64, 256, 0, stream>>>(x, W1, b1, gw, ha, habf, y, z);

    int aggblocks = (N_NODES + 31) / 32;  // 1563
    agg1_kernel<<<aggblocks, 256, 0, stream>>>(ha, habf, sedge, off, invcnt, y, z, gb,
                                               gw + 2 * HID, hbbf, y2, z2);
    agg2_kernel<<<aggblocks, 256, 0, stream>>>(hbbf, ha, sedge, off, invcnt, y2, z2,
                                               gb + 1, W2, b2, out);
}

// Round 6
// 217.547 us; speedup vs baseline: 1.2938x; 1.0153x over previous
//
#include <hip/hip_runtime.h>
#include <math.h>

#define N_NODES 50000
#define N_EDGES 800000
#define NFEAT 256
#define HID 64
#define NCLS 40
#define EPS_RES 0.3f
#define SCAN_BLOCKS ((N_NODES + 255) / 256)  // 196
#define EB 32                 // edge chunks
#define CHUNK (N_EDGES / EB)  // 25000
#define NR 4                  // node ranges
#define RNG (N_NODES / NR)    // 12500 -> 50KB LDS histogram

typedef unsigned int uint;
typedef unsigned short ushort;
typedef __attribute__((ext_vector_type(8))) short short8v;   // bf16x8 MFMA A/B frag
typedef __attribute__((ext_vector_type(4))) float f32x4;     // MFMA C/D frag

__device__ __forceinline__ float bflo(uint u) { return __uint_as_float(u << 16); }
__device__ __forceinline__ float bfhi(uint u) { return __uint_as_float(u & 0xFFFF0000u); }
__device__ __forceinline__ uint bf16rne(float f) {
    uint u = __float_as_uint(f);
    return (u + 0x7FFFu + ((u >> 16) & 1u)) >> 16;
}
__device__ __forceinline__ uint bf16rne2(float a, float b) {
    return bf16rne(a) | (bf16rne(b) << 16);
}

// exact fp32 -> bf16_hi + bf16_lo split (Dekker-style; hi+lo reproduces x to ~2^-18 rel)
__device__ __forceinline__ void bfsplit(float v, ushort& h, ushort& l) {
    uint hb_ = bf16rne(v);
    float hf = __uint_as_float(hb_ << 16);
    uint lb_ = bf16rne(v - hf);
    h = (ushort)hb_;
    l = (ushort)lb_;
}

// tanh(x) = 1 - 2/(e^{2x}+1) via v_exp_f32 + v_rcp_f32 (~2 ulp; exact +-1 limits).
__device__ __forceinline__ float fast_tanh(float x) {
    float t = __builtin_amdgcn_exp2f(x * 2.885390081777927f);  // e^{2x}
    return 1.0f - 2.0f * __builtin_amdgcn_rcpf(t + 1.0f);
}

// ---------------- degree histograms via LDS binning: ZERO global atomics ----------------
__global__ __launch_bounds__(256) void hist_kernel(const int* __restrict__ row,
                                                   const int* __restrict__ col,
                                                   int* __restrict__ degM,
                                                   int* __restrict__ cntM,
                                                   int* __restrict__ rank_local) {
    __shared__ int hist[RNG];
    int t = threadIdx.x;
    int chunk = blockIdx.x;
    int lo = blockIdx.y * RNG;
    int side = blockIdx.z;
    for (int j = t; j < RNG; j += 256) hist[j] = 0;
    __syncthreads();
    const int* idx = side ? col : row;
    int e0 = chunk * CHUNK;
    if (side == 0) {
        for (int base = 0; base < CHUNK; base += 1024) {
            int vb[4];
#pragma unroll
            for (int j = 0; j < 4; j++) {
                int i = base + j * 256 + t;
                vb[j] = (i < CHUNK) ? idx[e0 + i] : -1;
            }
#pragma unroll
            for (int j = 0; j < 4; j++) {
                uint v = (uint)(vb[j] - lo);
                if (v < RNG) atomicAdd(&hist[v], 1);
            }
        }
    } else {
        for (int base = 0; base < CHUNK; base += 1024) {
            int vb[4], ib[4];
#pragma unroll
            for (int j = 0; j < 4; j++) {
                int i = base + j * 256 + t;
                ib[j] = i;
                vb[j] = (i < CHUNK) ? idx[e0 + i] : -1;
            }
#pragma unroll
            for (int j = 0; j < 4; j++) {
                uint v = (uint)(vb[j] - lo);
                if (v < RNG) rank_local[e0 + ib[j]] = atomicAdd(&hist[v], 1);
            }
        }
    }
    __syncthreads();
    int* M = side ? cntM : degM;
    for (int j = t; j < RNG; j += 256) M[chunk * N_NODES + lo + j] = hist[j];
}

// ---------------- scan1: chunk-reduce (nd/invcnt + in-place cntM bases) + block scan ----
__device__ __forceinline__ int block_excl_scan_256(int v, int t, int* wsum) {
    int lane = t & 63, w = t >> 6;
    int sv = v;
#pragma unroll
    for (int d = 1; d < 64; d <<= 1) {
        int o = __shfl_up(sv, d);
        if (lane >= d) sv += o;
    }
    if (lane == 63) wsum[w] = sv;
    __syncthreads();
    int add = 0;
    for (int i = 0; i < w; i++) add += wsum[i];
    return sv + add - v;
}

__global__ void scan1_kernel(const int* __restrict__ degM, int* __restrict__ cntM,
                             int* __restrict__ off, int* __restrict__ bsum,
                             float* __restrict__ nd, float* __restrict__ invcnt) {
    __shared__ int wsum[4];
    int t = threadIdx.x;
    int idx = blockIdx.x * 256 + t;
    int v = 0;
    if (idx < N_NODES) {
        int sD = 0;
#pragma unroll
        for (int c = 0; c < EB; c++) sD += degM[c * N_NODES + idx];
        int run = 0;
#pragma unroll
        for (int c = 0; c < EB; c++) {
            int cv = cntM[c * N_NODES + idx];
            cntM[c * N_NODES + idx] = run;  // exclusive base for this chunk within bucket
            run += cv;
        }
        v = run;
        if (sD < 1) sD = 1;
        nd[idx] = rsqrtf((float)sD);
        int cc = run; if (cc < 1) cc = 1;
        invcnt[idx] = 1.0f / (float)cc;
    }
    int excl = block_excl_scan_256(v, t, wsum);
    if (idx < N_NODES) off[idx] = excl;
    if (t == 255) bsum[blockIdx.x] = excl + v;
}

__global__ void scan2_kernel(int* __restrict__ bsum) {
    __shared__ int wsum[4];
    int t = threadIdx.x;
    int v = (t < SCAN_BLOCKS) ? bsum[t] : 0;
    int excl = block_excl_scan_256(v, t, wsum);
    if (t < SCAN_BLOCKS) bsum[t] = excl;
}

__global__ void scan3_kernel(int* __restrict__ off, const int* __restrict__ bsum) {
    int t = threadIdx.x;
    int idx = blockIdx.x * 256 + t;
    if (idx < N_NODES) off[idx] += bsum[blockIdx.x];
    if (idx == 0) off[N_NODES] = N_EDGES;
}

// ---------------- CSR scatter: atomic-free, one 8B store per edge ----------------
__global__ void scatter_kernel(const int* __restrict__ row, const int* __restrict__ col,
                               const int* __restrict__ rank_local, const int* __restrict__ cntM,
                               const int* __restrict__ off, const float* __restrict__ nd,
                               int2* __restrict__ sedge) {
    int e = blockIdx.x * 256 + threadIdx.x;
    int r = row[e], c = col[e];
    int ch = e / CHUNK;
    int p = off[c] + cntM[ch * N_NODES + c] + rank_local[e];
    int2 se;
    se.x = r;
    se.y = __float_as_int(nd[r] * nd[c]);
    sedge[p] = se;
}

// ---------------- input projection via MFMA bf16x3 (error-free split) -------------------
__global__ __launch_bounds__(256) void proj_kernel(const float* __restrict__ x,
                                                   const float* __restrict__ W1,
                                                   const float* __restrict__ b1,
                                                   const float* __restrict__ gw,
                                                   float* __restrict__ ha,
                                                   ushort* __restrict__ habf,
                                                   float* __restrict__ y,
                                                   float* __restrict__ z) {
    __shared__ ushort smem[4 * 64 * 72];  // 36,864 B
    ushort* xs_h = smem;
    ushort* xs_l = smem + 4608;
    ushort* ws_h = smem + 9216;
    ushort* ws_l = smem + 13824;
    int t = threadIdx.x;
    int nb = blockIdx.x * 64;
    int lane = t & 63, w = t >> 6;
    int l15 = lane & 15, g = lane >> 4;
    int hbase = 16 * w + 4 * g;

    f32x4 acc[4];
#pragma unroll
    for (int hb = 0; hb < 4; hb++) acc[hb] = (f32x4)0.f;

    for (int kc = 0; kc < NFEAT; kc += 64) {
        __syncthreads();
#pragma unroll
        for (int i = 0; i < 4; i++) {
            int idx = t + 256 * i;
            int r_ = idx >> 4;     // 0..63 row (node-local for X, hid for W)
            int kq = idx & 15;     // float4 slot in the 64-wide K chunk
            int gn = nb + r_;
            float4 v = make_float4(0.f, 0.f, 0.f, 0.f);
            if (gn < N_NODES) v = *(const float4*)(x + (size_t)gn * NFEAT + kc + kq * 4);
            ushort4 h4, l4;
            bfsplit(v.x, h4.x, l4.x);
            bfsplit(v.y, h4.y, l4.y);
            bfsplit(v.z, h4.z, l4.z);
            bfsplit(v.w, h4.w, l4.w);
            *(ushort4*)(xs_h + r_ * 72 + kq * 4) = h4;
            *(ushort4*)(xs_l + r_ * 72 + kq * 4) = l4;
            float4 wv = *(const float4*)(W1 + (size_t)r_ * NFEAT + kc + kq * 4);
            bfsplit(wv.x, h4.x, l4.x);
            bfsplit(wv.y, h4.y, l4.y);
            bfsplit(wv.z, h4.z, l4.z);
            bfsplit(wv.w, h4.w, l4.w);
            *(ushort4*)(ws_h + r_ * 72 + kq * 4) = h4;
            *(ushort4*)(ws_l + r_ * 72 + kq * 4) = l4;
        }
        __syncthreads();
#pragma unroll
        for (int ko = 0; ko < 2; ko++) {
            int koff = ko * 32 + g * 8;  // K-octet for this lane
            short8v a_h = *(const short8v*)(xs_h + (w * 16 + l15) * 72 + koff);
            short8v a_l = *(const short8v*)(xs_l + (w * 16 + l15) * 72 + koff);
            short8v b_h[4], b_l[4];
#pragma unroll
            for (int hb = 0; hb < 4; hb++) {
                b_h[hb] = *(const short8v*)(ws_h + (hb * 16 + l15) * 72 + koff);
                b_l[hb] = *(const short8v*)(ws_l + (hb * 16 + l15) * 72 + koff);
            }
#pragma unroll
            for (int hb = 0; hb < 4; hb++) {
                acc[hb] = __builtin_amdgcn_mfma_f32_16x16x32_bf16(a_h, b_h[hb], acc[hb], 0, 0, 0);
                acc[hb] = __builtin_amdgcn_mfma_f32_16x16x32_bf16(a_h, b_l[hb], acc[hb], 0, 0, 0);
                acc[hb] = __builtin_amdgcn_mfma_f32_16x16x32_bf16(a_l, b_h[hb], acc[hb], 0, 0, 0);
            }
        }
    }
    // ---- epilogue: acc -> LDS (node-major) -> coalesced stores + y/z partials ----
    __syncthreads();
    float* hsf = (float*)smem;            // [64][68] fp32, 17,408 B
    float* ypart = hsf + 64 * 68;         // [64][16]
    float* zpart = ypart + 1024;          // [64][16]
#pragma unroll
    for (int hb = 0; hb < 4; hb++)
#pragma unroll
        for (int r = 0; r < 4; r++) {
            int nl = w * 16 + g * 4 + r;          // node-local row
            hsf[nl * 68 + hb * 16 + l15] = acc[hb][r];
        }
    __syncthreads();
    float4 bias = *(const float4*)(b1 + hbase);
    float4 wa4 = *(const float4*)(gw + hbase);
    float4 wb4 = *(const float4*)(gw + HID + hbase);
    int slot = w * 4 + g;  // 0..15
#pragma unroll
    for (int j = 0; j < 4; j++) {
        int rowl = l15 + 16 * j;
        int gn = nb + rowl;
        float4 hv = *(const float4*)(hsf + rowl * 68 + hbase);
        float4 o;
        o.x = fmaxf(hv.x + bias.x, 0.f);
        o.y = fmaxf(hv.y + bias.y, 0.f);
        o.z = fmaxf(hv.z + bias.z, 0.f);
        o.w = fmaxf(hv.w + bias.w, 0.f);
        if (gn < N_NODES) {
            *(float4*)(ha + (size_t)gn * HID + hbase) = o;
            uint2 pk;
            pk.x = bf16rne2(o.x, o.y);
            pk.y = bf16rne2(o.z, o.w);
            *(uint2*)(habf + (size_t)gn * HID + hbase) = pk;
        }
        ypart[rowl * 16 + slot] = o.x * wa4.x + o.y * wa4.y + o.z * wa4.z + o.w * wa4.w;
        zpart[rowl * 16 + slot] = o.x * wb4.x + o.y * wb4.y + o.z * wb4.z + o.w * wb4.w;
    }
    __syncthreads();
    if (t < 64 && nb + t < N_NODES) {
        float sa = 0.f, sb = 0.f;
#pragma unroll
        for (int s = 0; s < 16; s++) { sa += ypart[t * 16 + s]; sb += zpart[t * 16 + s]; }
        y[nb + t] = sa;
        z[nb + t] = sb;
    }
}

// ---------------- group-per-node CSR aggregation core, 2-edge ILP -----------------------
// Wave = 8 groups x 8 lanes; each group owns ONE node's full edge list and processes an
// even/odd PAIR of edges per iteration into independent accumulator sets (accE/accO,
// summed at the end; fp32 reorder ~1e-6, far under the bf16-dominated tolerance).
// Doubles in-flight gathers (4 uint4 per lane vs 2) and halves the trip count
// (ceil(maxdeg/2)) -> latency-bound loop runs ~2x denser. Invalid slots clamp to
// edge 0 with nde=0.
__device__ __forceinline__ void agg_group8(const ushort* __restrict__ hbf,
                                           const int2* __restrict__ sedge,
                                           const float* __restrict__ yv,
                                           float zc, int e0, int d, int c8,
                                           float acc[8], float& gs_out) {
    float accE[8], accO[8];
#pragma unroll
    for (int i = 0; i < 8; i++) { accE[i] = 0.f; accO[i] = 0.f; }
    float gsE = 0.f, gsO = 0.f;
    int m = d;
    m = max(m, __shfl_xor(m, 8));
    m = max(m, __shfl_xor(m, 16));
    m = max(m, __shfl_xor(m, 32));
    int mp = (m + 1) >> 1;  // pair count
    if (mp > 0) {
#define LOADSE(p, seE, seO, ndeE, ndeO)                                         \
        {   int k2_ = 2 * (p);                                                  \
            seE = sedge[(k2_ < d) ? e0 + k2_ : 0];                              \
            ndeE = (k2_ < d) ? __int_as_float(seE.y) : 0.f;                     \
            seO = sedge[(k2_ + 1 < d) ? e0 + k2_ + 1 : 0];                      \
            ndeO = (k2_ + 1 < d) ? __int_as_float(seO.y) : 0.f; }
#define LOADUY(seE, seO, yE, yO, uE, uO)                                        \
        {   yE = yv[seE.x];                                                     \
            uE = *(const uint4*)(hbf + (size_t)seE.x * HID + c8);               \
            yO = yv[seO.x];                                                     \
            uO = *(const uint4*)(hbf + (size_t)seO.x * HID + c8); }
        int2 seEA, seOA, seEB, seOB, seEC, seOC;
        float ndeEA, ndeOA, ndeEB, ndeOB, ndeEC, ndeOC;
        float yEA, yOA, yEB, yOB;
        uint4 uEA, uOA, uEB, uOB;
        LOADSE(0, seEA, seOA, ndeEA, ndeOA);
        LOADSE(1, seEB, seOB, ndeEB, ndeOB);
        LOADSE(2, seEC, seOC, ndeEC, ndeOC);
        LOADUY(seEA, seOA, yEA, yOA, uEA, uOA);
        LOADUY(seEB, seOB, yEB, yOB, uEB, uOB);
        for (int p = 0; p < mp; ++p) {
            // issue gathers for pair C (consumed 2 iterations from now)
            float yEC, yOC; uint4 uEC, uOC;
            LOADUY(seEC, seOC, yEC, yOC, uEC, uOC);
            // sedge for pair D (3 pairs ahead); clamp keeps reads in-bounds
            int2 seED, seOD; float ndeED, ndeOD;
            LOADSE(p + 3, seED, seOD, ndeED, ndeOD);
            // consume pair A (nde=0 kills invalid slots)
            float gvE = fast_tanh(yEA + zc) * ndeEA;
            accE[0] += gvE * bflo(uEA.x);
            accE[1] += gvE * bfhi(uEA.x);
            accE[2] += gvE * bflo(uEA.y);
            accE[3] += gvE * bfhi(uEA.y);
            accE[4] += gvE * bflo(uEA.z);
            accE[5] += gvE * bfhi(uEA.z);
            accE[6] += gvE * bflo(uEA.w);
            accE[7] += gvE * bfhi(uEA.w);
            gsE += gvE;
            float gvO = fast_tanh(yOA + zc) * ndeOA;
            accO[0] += gvO * bflo(uOA.x);
            accO[1] += gvO * bfhi(uOA.x);
            accO[2] += gvO * bflo(uOA.y);
            accO[3] += gvO * bfhi(uOA.y);
            accO[4] += gvO * bflo(uOA.z);
            accO[5] += gvO * bfhi(uOA.z);
            accO[6] += gvO * bflo(uOA.w);
            accO[7] += gvO * bfhi(uOA.w);
            gsO += gvO;
            // rotate pipeline registers
            yEA = yEB; uEA = uEB; ndeEA = ndeEB;
            yOA = yOB; uOA = uOB; ndeOA = ndeOB;
            yEB = yEC; uEB = uEC; ndeEB = ndeEC;
            yOB = yOC; uOB = uOC; ndeOB = ndeOC;
            seEC = seED; seOC = seOD; ndeEC = ndeED; ndeOC = ndeOD;
        }
#undef LOADSE
#undef LOADUY
    }
#pragma unroll
    for (int i = 0; i < 8; i++) acc[i] = accE[i] + accO[i];
    gs_out = gsE + gsO;
}

// ---------------- layer 1 agg + fused y2/z2; writes bf16 hbbf only ----------------
__global__ __launch_bounds__(256) void agg1_kernel(
        const float* __restrict__ ha, const ushort* __restrict__ habf,
        const int2* __restrict__ sedge, const int* __restrict__ off,
        const float* __restrict__ invcnt, const float* __restrict__ y,
        const float* __restrict__ z, const float* __restrict__ gb,
        const float* __restrict__ gw2, ushort* __restrict__ hbbf,
        float* __restrict__ y2, float* __restrict__ z2) {
    int t = threadIdx.x;
    int lane = t & 63;
    int ln = t >> 3;  // 0..31 local node
    int node = blockIdx.x * 32 + ln;
    int nc = (node < N_NODES) ? node : (N_NODES - 1);
    int c8 = (lane & 7) * 8;
    int e0 = off[nc];
    int e1 = off[nc + 1];
    int d = (node < N_NODES) ? (e1 - e0) : 0;
    float zc = z[nc] + gb[0];
    float acc[8]; float gs;
    agg_group8(habf, sedge, y, zc, e0, d, c8, acc, gs);
    float invc = invcnt[nc];
    float4 ra = *(const float4*)(ha + (size_t)nc * HID + c8);
    float4 rb = *(const float4*)(ha + (size_t)nc * HID + c8 + 4);
    float raw8[8] = {ra.x, ra.y, ra.z, ra.w, rb.x, rb.y, rb.z, rb.w};
    float o[8];
#pragma unroll
    for (int i = 0; i < 8; i++) o[i] = EPS_RES * raw8[i] + (acc[i] + gs * raw8[i]) * invc;
    if (node < N_NODES) {
        uint4 pk;
        pk.x = bf16rne2(o[0], o[1]);
        pk.y = bf16rne2(o[2], o[3]);
        pk.z = bf16rne2(o[4], o[5]);
        pk.w = bf16rne2(o[6], o[7]);
        *(uint4*)(hbbf + (size_t)nc * HID + c8) = pk;
    }
    float4 wa0 = *(const float4*)(gw2 + c8);
    float4 wa1 = *(const float4*)(gw2 + c8 + 4);
    float4 wb0 = *(const float4*)(gw2 + HID + c8);
    float4 wb1 = *(const float4*)(gw2 + HID + c8 + 4);
    float p = o[0] * wa0.x + o[1] * wa0.y + o[2] * wa0.z + o[3] * wa0.w
            + o[4] * wa1.x + o[5] * wa1.y + o[6] * wa1.z + o[7] * wa1.w;
    float qq = o[0] * wb0.x + o[1] * wb0.y + o[2] * wb0.z + o[3] * wb0.w
             + o[4] * wb1.x + o[5] * wb1.y + o[6] * wb1.z + o[7] * wb1.w;
#pragma unroll
    for (int s = 1; s < 8; s <<= 1) { p += __shfl_xor(p, s); qq += __shfl_xor(qq, s); }
    if ((lane & 7) == 0 && node < N_NODES) { y2[node] = p; z2[node] = qq; }
}

// ---------------- layer 2 agg + classifier + log_softmax ----------------
__global__ __launch_bounds__(256) void agg2_kernel(
        const ushort* __restrict__ hbbf, const float* __restrict__ ha,
        const int2* __restrict__ sedge, const int* __restrict__ off,
        const float* __restrict__ invcnt, const float* __restrict__ y2,
        const float* __restrict__ z2, const float* __restrict__ gb,
        const float* __restrict__ W2, const float* __restrict__ b2,
        float* __restrict__ out) {
    __shared__ float w2s[NCLS * 72];
    __shared__ float b2s[NCLS];
    __shared__ float hs[32 * 72];
    int t = threadIdx.x;
    for (int i = t; i < NCLS * HID; i += 256) w2s[(i >> 6) * 72 + (i & 63)] = W2[i];
    if (t < NCLS) b2s[t] = b2[t];
    int lane = t & 63;
    int ln = t >> 3;  // 0..31 local node
    int node = blockIdx.x * 32 + ln;
    int nc = (node < N_NODES) ? node : (N_NODES - 1);
    int c8 = (lane & 7) * 8;
    int e0 = off[nc];
    int e1 = off[nc + 1];
    int d = (node < N_NODES) ? (e1 - e0) : 0;
    float zc = z2[nc] + gb[0];
    float acc[8]; float gs;
    agg_group8(hbbf, sedge, y2, zc, e0, d, c8, acc, gs);
    float invc = invcnt[nc];
    uint4 hc = *(const uint4*)(hbbf + (size_t)nc * HID + c8);
    float hcv[8] = {bflo(hc.x), bfhi(hc.x), bflo(hc.y), bfhi(hc.y),
                    bflo(hc.z), bfhi(hc.z), bflo(hc.w), bfhi(hc.w)};
    float4 ra = *(const float4*)(ha + (size_t)nc * HID + c8);
    float4 rb = *(const float4*)(ha + (size_t)nc * HID + c8 + 4);
    float raw8[8] = {ra.x, ra.y, ra.z, ra.w, rb.x, rb.y, rb.z, rb.w};
    float4 o0, o1;
    o0.x = EPS_RES * raw8[0] + (acc[0] + gs * hcv[0]) * invc;
    o0.y = EPS_RES * raw8[1] + (acc[1] + gs * hcv[1]) * invc;
    o0.z = EPS_RES * raw8[2] + (acc[2] + gs * hcv[2]) * invc;
    o0.w = EPS_RES * raw8[3] + (acc[3] + gs * hcv[3]) * invc;
    o1.x = EPS_RES * raw8[4] + (acc[4] + gs * hcv[4]) * invc;
    o1.y = EPS_RES * raw8[5] + (acc[5] + gs * hcv[5]) * invc;
    o1.z = EPS_RES * raw8[6] + (acc[6] + gs * hcv[6]) * invc;
    o1.w = EPS_RES * raw8[7] + (acc[7] + gs * hcv[7]) * invc;
    *(float4*)(hs + ln * 72 + c8) = o0;
    *(float4*)(hs + ln * 72 + c8 + 4) = o1;
    __syncthreads();
    int k5 = t & 7;
    float lg[5];
#pragma unroll
    for (int j = 0; j < 5; j++) lg[j] = b2s[k5 + 8 * j];
    const float* hrow = hs + ln * 72;
#pragma unroll
    for (int j4 = 0; j4 < 16; j4++) {
        float4 h4 = *(const float4*)(hrow + j4 * 4);
#pragma unroll
        for (int j = 0; j < 5; j++) {
            float4 w4 = *(const float4*)(w2s + (k5 + 8 * j) * 72 + j4 * 4);
            lg[j] += h4.x * w4.x + h4.y * w4.y + h4.z * w4.z + h4.w * w4.w;
        }
    }
    float v = fmaxf(fmaxf(fmaxf(lg[0], lg[1]), fmaxf(lg[2], lg[3])), lg[4]);
    v = fmaxf(v, __shfl_xor(v, 1));
    v = fmaxf(v, __shfl_xor(v, 2));
    v = fmaxf(v, __shfl_xor(v, 4));
    float ex = 0.f;
#pragma unroll
    for (int j = 0; j < 5; j++) ex += __builtin_amdgcn_exp2f((lg[j] - v) * 1.44269504088896f);
    ex += __shfl_xor(ex, 1);
    ex += __shfl_xor(ex, 2);
    ex += __shfl_xor(ex, 4);
    float ls = v + __builtin_amdgcn_logf(ex) * 0.693147180559945f;
    if (node < N_NODES) {
#pragma unroll
        for (int j = 0; j < 5; j++) out[(size_t)node * NCLS + k5 + 8 * j] = lg[j] - ls;
    }
}

extern "C" void kernel_launch(void* const* d_in, const int* in_sizes, int n_in,
                              void* d_out, int out_size, void* d_ws, size_t ws_size,
                              hipStream_t stream) {
    const float* x  = (const float*)d_in[0];
    const int*   ei = (const int*)d_in[1];
    const float* W1 = (const float*)d_in[2];
    const float* b1 = (const float*)d_in[3];
    const float* W2 = (const float*)d_in[4];
    const float* b2 = (const float*)d_in[5];
    const float* gw = (const float*)d_in[6];
    const float* gb = (const float*)d_in[7];
    float* out = (float*)d_out;

    // ws layout (4B words): [sedge 2E][nd N][invcnt N][y N][z N][y2 N][z2 N]
    //   [ha 64N][habf 32N][hbbf 32N][off N+1][bsum 196]
    // degM/cntM (EB*N each = 12.8MB total) alias ha; rank_local (E) aliases habf.
    // All consumed by scatter before proj writes ha/habf (launch order). ~33.7 MB.
    int2*  sedge  = (int2*)d_ws;
    float* nd     = (float*)(sedge + N_EDGES);
    float* invcnt = nd + N_NODES;
    float* y      = invcnt + N_NODES;
    float* z      = y + N_NODES;
    float* y2     = z + N_NODES;
    float* z2     = y2 + N_NODES;
    float* ha     = z2 + N_NODES;
    ushort* habf  = (ushort*)(ha + (size_t)N_NODES * HID);
    ushort* hbbf  = habf + (size_t)N_NODES * HID;
    int*   off    = (int*)(hbbf + (size_t)N_NODES * HID);
    int*   bsum   = off + N_NODES + 1;
    int*   degM   = (int*)ha;                  // EB*N ints
    int*   cntM   = degM + (size_t)EB * N_NODES;  // EB*N ints (both inside ha's 64N)
    int*   rank_local = (int*)habf;            // E ints <= 32N words

    const int* row = ei;
    const int* col = ei + N_EDGES;

    hist_kernel<<<dim3(EB, NR, 2), 256, 0, stream>>>(row, col, degM, cntM, rank_local);
    scan1_kernel<<<SCAN_BLOCKS, 256, 0, stream>>>(degM, cntM, off, bsum, nd, invcnt);
    scan2_kernel<<<1, 256, 0, stream>>>(bsum);
    scan3_kernel<<<SCAN_BLOCKS, 256, 0, stream>>>(off, bsum);
    scatter_kernel<<<N_EDGES / 256, 256, 0, stream>>>(row, col, rank_local, cntM, off, nd, sedge);
    proj_kernel<<<(N_NODES + 63) / 64, 256, 0, stream>>>(x, W1, b1, gw, ha, habf, y, z);

    int aggblocks = (N_NODES + 31) / 32;  // 1563
    agg1_kernel<<<aggblocks, 256, 0, stream>>>(ha, habf, sedge, off, invcnt, y, z, gb,
                                               gw + 2 * HID, hbbf, y2, z2);
    agg2_kernel<<<aggblocks, 256, 0, stream>>>(hbbf, ha, sedge, off, invcnt, y2, z2,
                                               gb + 1, W2, b2, out);
}